// Round 1
// baseline (6085.513 us; speedup 1.0000x reference)
//
#include <hip/hip_runtime.h>
#include <math.h>

#define NB 64
#define DIM 128
#define ETOT 1048576

static const int NS_H[6] = {1024, 820, 656, 525, 420, 336};

// ---------------- utility ----------------
__global__ void fill_ones_kernel(float* p, int n) {
    int i = blockIdx.x * blockDim.x + threadIdx.x;
    if (i < n) p[i] = 1.0f;
}

// ---------------- linear: y = x @ W.T + b ----------------
// block: 128 threads, NPB nodes per block; thread j owns output feature j.
#define NPB 8
__global__ void linear_kernel(const float* __restrict__ x, const float* __restrict__ W,
                              const float* __restrict__ b, float* __restrict__ y, int N) {
    __shared__ float xs[NPB][DIM];
    int node0 = blockIdx.x * NPB;
    int j = threadIdx.x;
    for (int t = 0; t < NPB; t++) {
        int nd = node0 + t;
        xs[t][j] = (nd < N) ? x[nd * DIM + j] : 0.f;
    }
    __syncthreads();
    const float* wr = W + j * DIM;
    float bj = b[j];
    float acc[NPB];
#pragma unroll
    for (int t = 0; t < NPB; t++) acc[t] = bj;
    for (int d = 0; d < DIM; d++) {
        float wv = wr[d];
#pragma unroll
        for (int t = 0; t < NPB; t++) acc[t] += xs[t][d] * wv;
    }
    for (int t = 0; t < NPB; t++) {
        int nd = node0 + t;
        if (nd < N) y[nd * DIM + j] = acc[t];
    }
}

// ---------------- degree: deg[src] += valid ----------------
__global__ void deg_kernel(const int* __restrict__ src, const float* __restrict__ valid,
                           float* __restrict__ deg) {
    int e = blockIdx.x * blockDim.x + threadIdx.x;
    if (e < ETOT) {
        float v = valid[e];
        if (v != 0.f) atomicAdd(&deg[src[e]], v);
    }
}

// ---------------- self term: out = xl / (deg+1) ----------------
__global__ void self_kernel(const float* __restrict__ xl, const float* __restrict__ deg,
                            float* __restrict__ out, int N) {
    int i = blockIdx.x * blockDim.x + threadIdx.x;
    if (i < N * DIM) {
        int n = i >> 7;
        out[i] = xl[i] / (deg[n] + 1.0f);
    }
}

// ---------------- edge aggregation: out[dst] += norm * xl[src] ----------------
// 256 threads = 8 edges/block, 32 threads per edge (float4 each)
__global__ void agg_kernel(const int* __restrict__ src, const int* __restrict__ dst,
                           const float* __restrict__ valid, const float* __restrict__ deg,
                           const float* __restrict__ xl, float* __restrict__ out) {
    int t = threadIdx.x;
    int e = blockIdx.x * 8 + (t >> 5);
    int f4 = (t & 31);
    float v = valid[e];
    if (v == 0.f) return;
    int s = src[e], d = dst[e];
    float norm = rsqrtf((deg[s] + 1.0f) * (deg[d] + 1.0f)) * v;
    const float4* xsrc = (const float4*)(xl + (size_t)s * DIM);
    float4 val = xsrc[f4];
    float* od = out + (size_t)d * DIM;
    atomicAdd(&od[f4 * 4 + 0], norm * val.x);
    atomicAdd(&od[f4 * 4 + 1], norm * val.y);
    atomicAdd(&od[f4 * 4 + 2], norm * val.z);
    atomicAdd(&od[f4 * 4 + 3], norm * val.w);
}

__global__ void relu_kernel(float* p, int n) {
    int i = blockIdx.x * blockDim.x + threadIdx.x;
    if (i < n) p[i] = fmaxf(p[i], 0.f);
}

// ---------------- pool weight inverse norm ----------------
__global__ void invnorm_kernel(const float* __restrict__ pw, float* __restrict__ invn) {
    __shared__ float sh[DIM];
    int t = threadIdx.x;
    float v = pw[t];
    sh[t] = v * v;
    __syncthreads();
    for (int s = 64; s > 0; s >>= 1) {
        if (t < s) sh[t] += sh[t + s];
        __syncthreads();
    }
    if (t == 0) invn[0] = rsqrtf(sh[0]);
}

// ---------------- score: s = tanh(dot(x, pw) * invn) ----------------
__global__ void score_kernel(const float* __restrict__ x, const float* __restrict__ pw,
                             const float* __restrict__ invn, float* __restrict__ sc) {
    __shared__ float sh[DIM];
    int n = blockIdx.x;
    int t = threadIdx.x;
    sh[t] = x[(size_t)n * DIM + t] * pw[t];
    __syncthreads();
    for (int s = 64; s > 0; s >>= 1) {
        if (t < s) sh[t] += sh[t + s];
        __syncthreads();
    }
    if (t == 0) sc[n] = tanhf(sh[0] * invn[0]);
}

// ---------------- per-graph bitonic top-k sort ----------------
// comparator order: higher score first; ties -> lower index first (matches jax.lax.top_k)
__global__ void topk_sort_kernel(const float* __restrict__ sc, int n,
                                 float* __restrict__ skey_out, int* __restrict__ sidx_out) {
    __shared__ float key[1024];
    __shared__ int idx[1024];
    int g = blockIdx.x;
    for (int i = threadIdx.x; i < 1024; i += blockDim.x) {
        if (i < n) { key[i] = sc[g * n + i]; idx[i] = i; }
        else       { key[i] = -2.0f;         idx[i] = i; }  // tanh in (-1,1): -2 sorts last
    }
    __syncthreads();
    for (unsigned ksz = 2; ksz <= 1024; ksz <<= 1) {
        for (unsigned j = ksz >> 1; j > 0; j >>= 1) {
            for (unsigned i = threadIdx.x; i < 1024; i += blockDim.x) {
                unsigned ixj = i ^ j;
                if (ixj > i) {
                    float ka = key[i], kb = key[ixj];
                    int ia = idx[i], ib = idx[ixj];
                    bool aLess = (ka > kb) || (ka == kb && ia < ib); // a before b
                    bool up = ((i & ksz) == 0);
                    bool sw = up ? !aLess : aLess;
                    if (sw) { key[i] = kb; key[ixj] = ka; idx[i] = ib; idx[ixj] = ia; }
                }
            }
            __syncthreads();
        }
    }
    for (int i = threadIdx.x; i < 1024; i += blockDim.x) {
        skey_out[g * 1024 + i] = key[i];
        sidx_out[g * 1024 + i] = idx[i];
    }
}

// ---------------- build new_id (pre-memset to -1) ----------------
__global__ void topk_finish_kernel(const int* __restrict__ sidx, int* __restrict__ new_id,
                                   int n, int k) {
    int g = blockIdx.x;
    int t = threadIdx.x;
    if (t < k) new_id[g * n + sidx[g * 1024 + t]] = g * k + t;
}

// ---------------- gather pooled x: xn = x[perm] * s[perm] ----------------
__global__ void gather_kernel(const float* __restrict__ x, const float* __restrict__ skey,
                              const int* __restrict__ sidx, float* __restrict__ xn,
                              int n, int k) {
    int gj = blockIdx.x;
    int g = gj / k;
    int j = gj - g * k;
    int local = sidx[g * 1024 + j];
    float sval = skey[g * 1024 + j];
    xn[(size_t)gj * DIM + threadIdx.x] = x[((size_t)g * n + local) * DIM + threadIdx.x] * sval;
}

// ---------------- remap edges ----------------
__global__ void remap_kernel(int* __restrict__ src, int* __restrict__ dst,
                             float* __restrict__ valid, const int* __restrict__ new_id) {
    int e = blockIdx.x * blockDim.x + threadIdx.x;
    if (e < ETOT) {
        int s = new_id[src[e]];
        int d = new_id[dst[e]];
        float v = valid[e];
        v = (s >= 0 && d >= 0) ? v : 0.f;
        src[e] = s >= 0 ? s : 0;
        dst[e] = d >= 0 ? d : 0;
        valid[e] = v;
    }
}

// ---------------- readout: h[g] += [max_k ; mean_k] ----------------
__global__ void readout_kernel(const float* __restrict__ xn, float* __restrict__ h, int k) {
    int g = blockIdx.x, t = threadIdx.x;
    const float* base = xn + (size_t)g * k * DIM + t;
    float mx = -INFINITY, sm = 0.f;
    for (int j = 0; j < k; j++) {
        float v = base[(size_t)j * DIM];
        mx = fmaxf(mx, v);
        sm += v;
    }
    h[g * 256 + t] += mx;
    h[g * 256 + 128 + t] += sm / (float)k;
}

// ---------------- MLP head + log_softmax ----------------
__global__ void head_kernel(const float* __restrict__ h,
                            const float* __restrict__ l1w, const float* __restrict__ l1b,
                            const float* __restrict__ l2w, const float* __restrict__ l2b,
                            const float* __restrict__ l3w, const float* __restrict__ l3b,
                            float* __restrict__ out) {
    __shared__ float hr[256];
    __shared__ float h1[128];
    __shared__ float h2[64];
    __shared__ float lz[2];
    int g = blockIdx.x, t = threadIdx.x;
    hr[t] = h[g * 256 + t];
    hr[t + 128] = h[g * 256 + 128 + t];
    __syncthreads();
    float acc = l1b[t];
    for (int d = 0; d < 256; d++) acc += hr[d] * l1w[t * 256 + d];
    h1[t] = fmaxf(acc, 0.f);
    __syncthreads();
    if (t < 64) {
        float a2 = l2b[t];
        for (int d = 0; d < 128; d++) a2 += h1[d] * l2w[t * 128 + d];
        h2[t] = fmaxf(a2, 0.f);
    }
    __syncthreads();
    if (t < 2) {
        float a3 = l3b[t];
        for (int d = 0; d < 64; d++) a3 += h2[d] * l3w[t * 64 + d];
        lz[t] = a3;
    }
    __syncthreads();
    if (t < 2) {
        float z0 = lz[0], z1 = lz[1];
        float m = fmaxf(z0, z1);
        float lse = m + logf(expf(z0 - m) + expf(z1 - m));
        out[g * 2 + t] = lz[t] - lse;
    }
}

extern "C" void kernel_launch(void* const* d_in, const int* in_sizes, int n_in,
                              void* d_out, int out_size, void* d_ws, size_t ws_size,
                              hipStream_t stream) {
    const float* x_in = (const float*)d_in[0];
    const int* edge_index = (const int*)d_in[1];
    // d_in[2] = batch (unused; structure is fixed)
    const float *cw[5], *cb[5], *pw[5];
    for (int i = 0; i < 5; i++) {
        cw[i] = (const float*)d_in[3 + 3 * i];
        cb[i] = (const float*)d_in[4 + 3 * i];
        pw[i] = (const float*)d_in[5 + 3 * i];
    }
    const float* l1w = (const float*)d_in[18];
    const float* l1b = (const float*)d_in[19];
    const float* l2w = (const float*)d_in[20];
    const float* l2b = (const float*)d_in[21];
    const float* l3w = (const float*)d_in[22];
    const float* l3b = (const float*)d_in[23];
    float* out = (float*)d_out;

    char* w = (char*)d_ws;
    float* xA   = (float*)w; w += (size_t)65536 * DIM * 4;   // gcn output
    float* xB   = (float*)w; w += (size_t)65536 * DIM * 4;   // pooled x
    float* xL   = (float*)w; w += (size_t)65536 * DIM * 4;   // linear output
    int*   src  = (int*)w;   w += (size_t)ETOT * 4;
    int*   dst  = (int*)w;   w += (size_t)ETOT * 4;
    float* valid= (float*)w; w += (size_t)ETOT * 4;
    float* deg  = (float*)w; w += (size_t)65536 * 4;
    float* score= (float*)w; w += (size_t)65536 * 4;
    float* skey = (float*)w; w += (size_t)NB * 1024 * 4;
    int*   sidx = (int*)w;   w += (size_t)NB * 1024 * 4;
    int*   newid= (int*)w;   w += (size_t)65536 * 4;
    float* hsum = (float*)w; w += (size_t)NB * 256 * 4;
    float* invn = (float*)w; w += 4;

    hipMemcpyAsync(src, edge_index, (size_t)ETOT * 4, hipMemcpyDeviceToDevice, stream);
    hipMemcpyAsync(dst, edge_index + ETOT, (size_t)ETOT * 4, hipMemcpyDeviceToDevice, stream);
    fill_ones_kernel<<<ETOT / 256, 256, 0, stream>>>(valid, ETOT);
    hipMemsetAsync(hsum, 0, (size_t)NB * 256 * 4, stream);

    const float* xin = x_in;
    for (int i = 0; i < 5; i++) {
        int n = NS_H[i], k = NS_H[i + 1];
        int N = NB * n, K = NB * k;

        linear_kernel<<<(N + NPB - 1) / NPB, 128, 0, stream>>>(xin, cw[i], cb[i], xL, N);
        hipMemsetAsync(deg, 0, (size_t)N * 4, stream);
        deg_kernel<<<ETOT / 256, 256, 0, stream>>>(src, valid, deg);
        self_kernel<<<(N * DIM + 255) / 256, 256, 0, stream>>>(xL, deg, xA, N);
        agg_kernel<<<ETOT / 8, 256, 0, stream>>>(src, dst, valid, deg, xL, xA);
        relu_kernel<<<(N * DIM + 255) / 256, 256, 0, stream>>>(xA, N * DIM);
        invnorm_kernel<<<1, 128, 0, stream>>>(pw[i], invn);
        score_kernel<<<N, 128, 0, stream>>>(xA, pw[i], invn, score);
        topk_sort_kernel<<<NB, 512, 0, stream>>>(score, n, skey, sidx);
        hipMemsetAsync(newid, 0xFF, (size_t)N * 4, stream);
        topk_finish_kernel<<<NB, 1024, 0, stream>>>(sidx, newid, n, k);
        gather_kernel<<<K, 128, 0, stream>>>(xA, skey, sidx, xB, n, k);
        remap_kernel<<<ETOT / 256, 256, 0, stream>>>(src, dst, valid, newid);
        readout_kernel<<<NB, 128, 0, stream>>>(xB, hsum, k);

        xin = xB;
    }

    head_kernel<<<NB, 128, 0, stream>>>(hsum, l1w, l1b, l2w, l2b, l3w, l3b, out);
}

// Round 2
// 2342.134 us; speedup vs baseline: 2.5983x; 2.5983x over previous
//
#include <hip/hip_runtime.h>
#include <math.h>

#define NB 64
#define DIM 128
#define ETOT 1048576

static const int NS_H[6] = {1024, 820, 656, 525, 420, 336};

// ---------------- utility ----------------
__global__ void fill_ones_kernel(float* p, int n) {
    int i = blockIdx.x * blockDim.x + threadIdx.x;
    if (i < n) p[i] = 1.0f;
}

// ---------------- linear: y = x @ W.T + b ----------------
#define NPB 8
__global__ void linear_kernel(const float* __restrict__ x, const float* __restrict__ W,
                              const float* __restrict__ b, float* __restrict__ y, int N) {
    __shared__ float xs[NPB][DIM];
    int node0 = blockIdx.x * NPB;
    int j = threadIdx.x;
    for (int t = 0; t < NPB; t++) {
        int nd = node0 + t;
        xs[t][j] = (nd < N) ? x[nd * DIM + j] : 0.f;
    }
    __syncthreads();
    const float* wr = W + j * DIM;
    float bj = b[j];
    float acc[NPB];
#pragma unroll
    for (int t = 0; t < NPB; t++) acc[t] = bj;
    for (int d = 0; d < DIM; d++) {
        float wv = wr[d];
#pragma unroll
        for (int t = 0; t < NPB; t++) acc[t] += xs[t][d] * wv;
    }
    for (int t = 0; t < NPB; t++) {
        int nd = node0 + t;
        if (nd < N) y[nd * DIM + j] = acc[t];
    }
}

// ---------------- count: deg[src] += 1 (float), cnt[dst] += 1 (int) ----------------
__global__ void count_kernel(const int* __restrict__ src, const int* __restrict__ dst,
                             const float* __restrict__ valid,
                             float* __restrict__ degf, int* __restrict__ cnt) {
    int e = blockIdx.x * blockDim.x + threadIdx.x;
    if (e < ETOT) {
        if (valid[e] != 0.f) {
            atomicAdd(&degf[src[e]], 1.0f);
            atomicAdd(&cnt[dst[e]], 1);
        }
    }
}

// ---------------- exclusive scan over cnt[0..N) -> eoff[0..N], cursor ----------------
__global__ void scan_kernel(const int* __restrict__ cnt, int* __restrict__ eoff,
                            int* __restrict__ cursor, int N) {
    __shared__ int sh[1024];
    int t = threadIdx.x;
    int chunk = (N + 1023) / 1024;
    int start = t * chunk;
    int end = start + chunk; if (end > N) end = N;
    int sum = 0;
    for (int i = start; i < end; i++) sum += cnt[i];
    sh[t] = sum;
    __syncthreads();
    // Hillis-Steele inclusive scan
    for (int off = 1; off < 1024; off <<= 1) {
        int v = (t >= off) ? sh[t - off] : 0;
        __syncthreads();
        sh[t] += v;
        __syncthreads();
    }
    int excl = sh[t] - sum;
    int run = excl;
    for (int i = start; i < end; i++) {
        eoff[i] = run;
        cursor[i] = run;
        run += cnt[i];
    }
    if (t == 1023) eoff[N] = excl + sum;
}

// ---------------- scatter valid edges into CSR by dst ----------------
__global__ void scatter_kernel(const int* __restrict__ src, const int* __restrict__ dst,
                               const float* __restrict__ valid,
                               int* __restrict__ cursor, int* __restrict__ esrc_s) {
    int e = blockIdx.x * blockDim.x + threadIdx.x;
    if (e < ETOT) {
        if (valid[e] != 0.f) {
            int pos = atomicAdd(&cursor[dst[e]], 1);
            esrc_s[pos] = src[e];
        }
    }
}

// ---------------- fused aggregate + self + relu + score ----------------
// 32 lanes per node, float4 per lane; 8 nodes per 256-thread block.
__global__ void fused_agg_kernel(const float* __restrict__ xL, const int* __restrict__ esrc,
                                 const int* __restrict__ eoff, const float* __restrict__ degf,
                                 const float* __restrict__ pw, const float* __restrict__ invn,
                                 float* __restrict__ xA, float* __restrict__ score, int N) {
    int t = threadIdx.x;
    int n = blockIdx.x * 8 + (t >> 5);
    int lane = t & 31;
    if (n >= N) return;
    float dn = degf[n] + 1.0f;
    float dsn = rsqrtf(dn);
    const float4* selfp = (const float4*)(xL + (size_t)n * DIM);
    float4 sv = selfp[lane];
    float inv_dn = 1.0f / dn;
    float4 acc = make_float4(sv.x * inv_dn, sv.y * inv_dn, sv.z * inv_dn, sv.w * inv_dn);
    int s0 = eoff[n], s1 = eoff[n + 1];
    for (int j = s0; j < s1; j++) {
        int s = esrc[j];
        float norm = dsn * rsqrtf(degf[s] + 1.0f);
        const float4* xp = (const float4*)(xL + (size_t)s * DIM);
        float4 xv = xp[lane];
        acc.x += norm * xv.x;
        acc.y += norm * xv.y;
        acc.z += norm * xv.z;
        acc.w += norm * xv.w;
    }
    acc.x = fmaxf(acc.x, 0.f);
    acc.y = fmaxf(acc.y, 0.f);
    acc.z = fmaxf(acc.z, 0.f);
    acc.w = fmaxf(acc.w, 0.f);
    ((float4*)(xA + (size_t)n * DIM))[lane] = acc;
    // score = tanh(dot(relu_out, pw) * invn)
    const float4* pwp = (const float4*)pw;
    float4 pv = pwp[lane];
    float dot = acc.x * pv.x + acc.y * pv.y + acc.z * pv.z + acc.w * pv.w;
    for (int off = 16; off >= 1; off >>= 1) dot += __shfl_xor(dot, off, 32);
    if (lane == 0) score[n] = tanhf(dot * invn[0]);
}

// ---------------- pool weight inverse norm ----------------
__global__ void invnorm_kernel(const float* __restrict__ pw, float* __restrict__ invn) {
    __shared__ float sh[DIM];
    int t = threadIdx.x;
    float v = pw[t];
    sh[t] = v * v;
    __syncthreads();
    for (int s = 64; s > 0; s >>= 1) {
        if (t < s) sh[t] += sh[t + s];
        __syncthreads();
    }
    if (t == 0) invn[0] = rsqrtf(sh[0]);
}

// ---------------- per-graph bitonic top-k sort ----------------
__global__ void topk_sort_kernel(const float* __restrict__ sc, int n,
                                 float* __restrict__ skey_out, int* __restrict__ sidx_out) {
    __shared__ float key[1024];
    __shared__ int idx[1024];
    int g = blockIdx.x;
    for (int i = threadIdx.x; i < 1024; i += blockDim.x) {
        if (i < n) { key[i] = sc[g * n + i]; idx[i] = i; }
        else       { key[i] = -2.0f;         idx[i] = i; }
    }
    __syncthreads();
    for (unsigned ksz = 2; ksz <= 1024; ksz <<= 1) {
        for (unsigned j = ksz >> 1; j > 0; j >>= 1) {
            for (unsigned i = threadIdx.x; i < 1024; i += blockDim.x) {
                unsigned ixj = i ^ j;
                if (ixj > i) {
                    float ka = key[i], kb = key[ixj];
                    int ia = idx[i], ib = idx[ixj];
                    bool aLess = (ka > kb) || (ka == kb && ia < ib);
                    bool up = ((i & ksz) == 0);
                    bool sw = up ? !aLess : aLess;
                    if (sw) { key[i] = kb; key[ixj] = ka; idx[i] = ib; idx[ixj] = ia; }
                }
            }
            __syncthreads();
        }
    }
    for (int i = threadIdx.x; i < 1024; i += blockDim.x) {
        skey_out[g * 1024 + i] = key[i];
        sidx_out[g * 1024 + i] = idx[i];
    }
}

__global__ void topk_finish_kernel(const int* __restrict__ sidx, int* __restrict__ new_id,
                                   int n, int k) {
    int g = blockIdx.x;
    int t = threadIdx.x;
    if (t < k) new_id[g * n + sidx[g * 1024 + t]] = g * k + t;
}

__global__ void gather_kernel(const float* __restrict__ x, const float* __restrict__ skey,
                              const int* __restrict__ sidx, float* __restrict__ xn,
                              int n, int k) {
    int gj = blockIdx.x;
    int g = gj / k;
    int j = gj - g * k;
    int local = sidx[g * 1024 + j];
    float sval = skey[g * 1024 + j];
    xn[(size_t)gj * DIM + threadIdx.x] = x[((size_t)g * n + local) * DIM + threadIdx.x] * sval;
}

__global__ void remap_kernel(int* __restrict__ src, int* __restrict__ dst,
                             float* __restrict__ valid, const int* __restrict__ new_id) {
    int e = blockIdx.x * blockDim.x + threadIdx.x;
    if (e < ETOT) {
        int s = new_id[src[e]];
        int d = new_id[dst[e]];
        float v = valid[e];
        v = (s >= 0 && d >= 0) ? v : 0.f;
        src[e] = s >= 0 ? s : 0;
        dst[e] = d >= 0 ? d : 0;
        valid[e] = v;
    }
}

__global__ void readout_kernel(const float* __restrict__ xn, float* __restrict__ h, int k) {
    int g = blockIdx.x, t = threadIdx.x;
    const float* base = xn + (size_t)g * k * DIM + t;
    float mx = -INFINITY, sm = 0.f;
    for (int j = 0; j < k; j++) {
        float v = base[(size_t)j * DIM];
        mx = fmaxf(mx, v);
        sm += v;
    }
    h[g * 256 + t] += mx;
    h[g * 256 + 128 + t] += sm / (float)k;
}

__global__ void head_kernel(const float* __restrict__ h,
                            const float* __restrict__ l1w, const float* __restrict__ l1b,
                            const float* __restrict__ l2w, const float* __restrict__ l2b,
                            const float* __restrict__ l3w, const float* __restrict__ l3b,
                            float* __restrict__ out) {
    __shared__ float hr[256];
    __shared__ float h1[128];
    __shared__ float h2[64];
    __shared__ float lz[2];
    int g = blockIdx.x, t = threadIdx.x;
    hr[t] = h[g * 256 + t];
    hr[t + 128] = h[g * 256 + 128 + t];
    __syncthreads();
    float acc = l1b[t];
    for (int d = 0; d < 256; d++) acc += hr[d] * l1w[t * 256 + d];
    h1[t] = fmaxf(acc, 0.f);
    __syncthreads();
    if (t < 64) {
        float a2 = l2b[t];
        for (int d = 0; d < 128; d++) a2 += h1[d] * l2w[t * 128 + d];
        h2[t] = fmaxf(a2, 0.f);
    }
    __syncthreads();
    if (t < 2) {
        float a3 = l3b[t];
        for (int d = 0; d < 64; d++) a3 += h2[d] * l3w[t * 64 + d];
        lz[t] = a3;
    }
    __syncthreads();
    if (t < 2) {
        float z0 = lz[0], z1 = lz[1];
        float m = fmaxf(z0, z1);
        float lse = m + logf(expf(z0 - m) + expf(z1 - m));
        out[g * 2 + t] = lz[t] - lse;
    }
}

extern "C" void kernel_launch(void* const* d_in, const int* in_sizes, int n_in,
                              void* d_out, int out_size, void* d_ws, size_t ws_size,
                              hipStream_t stream) {
    const float* x_in = (const float*)d_in[0];
    const int* edge_index = (const int*)d_in[1];
    const float *cw[5], *cb[5], *pw[5];
    for (int i = 0; i < 5; i++) {
        cw[i] = (const float*)d_in[3 + 3 * i];
        cb[i] = (const float*)d_in[4 + 3 * i];
        pw[i] = (const float*)d_in[5 + 3 * i];
    }
    const float* l1w = (const float*)d_in[18];
    const float* l1b = (const float*)d_in[19];
    const float* l2w = (const float*)d_in[20];
    const float* l2b = (const float*)d_in[21];
    const float* l3w = (const float*)d_in[22];
    const float* l3b = (const float*)d_in[23];
    float* out = (float*)d_out;

    char* w = (char*)d_ws;
    float* xA    = (float*)w; w += (size_t)65536 * DIM * 4;
    float* xB    = (float*)w; w += (size_t)65536 * DIM * 4;
    float* xL    = (float*)w; w += (size_t)65536 * DIM * 4;
    int*   src   = (int*)w;   w += (size_t)ETOT * 4;
    int*   dst   = (int*)w;   w += (size_t)ETOT * 4;
    float* valid = (float*)w; w += (size_t)ETOT * 4;
    int*   esrc_s= (int*)w;   w += (size_t)ETOT * 4;
    float* deg   = (float*)w; w += (size_t)65536 * 4;
    int*   cnt   = (int*)w;   w += (size_t)65536 * 4;
    int*   eoff  = (int*)w;   w += (size_t)(65536 + 1) * 4;
    int*   cursor= (int*)w;   w += (size_t)65536 * 4;
    float* score = (float*)w; w += (size_t)65536 * 4;
    float* skey  = (float*)w; w += (size_t)NB * 1024 * 4;
    int*   sidx  = (int*)w;   w += (size_t)NB * 1024 * 4;
    int*   newid = (int*)w;   w += (size_t)65536 * 4;
    float* hsum  = (float*)w; w += (size_t)NB * 256 * 4;
    float* invn  = (float*)w; w += 4;

    hipMemcpyAsync(src, edge_index, (size_t)ETOT * 4, hipMemcpyDeviceToDevice, stream);
    hipMemcpyAsync(dst, edge_index + ETOT, (size_t)ETOT * 4, hipMemcpyDeviceToDevice, stream);
    fill_ones_kernel<<<ETOT / 256, 256, 0, stream>>>(valid, ETOT);
    hipMemsetAsync(hsum, 0, (size_t)NB * 256 * 4, stream);

    const float* xin = x_in;
    for (int i = 0; i < 5; i++) {
        int n = NS_H[i], k = NS_H[i + 1];
        int N = NB * n, K = NB * k;

        linear_kernel<<<(N + NPB - 1) / NPB, 128, 0, stream>>>(xin, cw[i], cb[i], xL, N);

        hipMemsetAsync(deg, 0, (size_t)N * 4, stream);
        hipMemsetAsync(cnt, 0, (size_t)N * 4, stream);
        count_kernel<<<ETOT / 256, 256, 0, stream>>>(src, dst, valid, deg, cnt);
        scan_kernel<<<1, 1024, 0, stream>>>(cnt, eoff, cursor, N);
        scatter_kernel<<<ETOT / 256, 256, 0, stream>>>(src, dst, valid, cursor, esrc_s);

        invnorm_kernel<<<1, 128, 0, stream>>>(pw[i], invn);
        fused_agg_kernel<<<(N + 7) / 8, 256, 0, stream>>>(xL, esrc_s, eoff, deg, pw[i], invn,
                                                          xA, score, N);

        topk_sort_kernel<<<NB, 512, 0, stream>>>(score, n, skey, sidx);
        hipMemsetAsync(newid, 0xFF, (size_t)N * 4, stream);
        topk_finish_kernel<<<NB, 1024, 0, stream>>>(sidx, newid, n, k);
        gather_kernel<<<K, 128, 0, stream>>>(xA, skey, sidx, xB, n, k);
        remap_kernel<<<ETOT / 256, 256, 0, stream>>>(src, dst, valid, newid);
        readout_kernel<<<NB, 128, 0, stream>>>(xB, hsum, k);

        xin = xB;
    }

    head_kernel<<<NB, 128, 0, stream>>>(hsum, l1w, l1b, l2w, l2b, l3w, l3b, out);
}

// Round 3
// 1243.254 us; speedup vs baseline: 4.8948x; 1.8839x over previous
//
#include <hip/hip_runtime.h>
#include <math.h>

#define NB 64
#define DIM 128
#define ETOT 1048576
#define EPG 16384   // edges-per-graph region (ETOT / NB)

static const int NS_H[6] = {1024, 820, 656, 525, 420, 336};

// ---------------- utility ----------------
__global__ void fill_ones_kernel(float* p, int n) {
    int i = blockIdx.x * blockDim.x + threadIdx.x;
    if (i < n) p[i] = 1.0f;
}

// ---------------- linear: y = x @ W.T + b  (LDS-staged tiled fp32 GEMM) ----------------
// 256 threads, persistent blocks. W^T staged once per block (66KB), then loop over
// 128-node chunks: stage x^T (66KB), each thread computes an 8-node x 8-feat tile.
__global__ __launch_bounds__(256) void linear_kernel(const float* __restrict__ x,
                              const float* __restrict__ W, const float* __restrict__ b,
                              float* __restrict__ y, int N) {
    __shared__ float Wt[128][129];   // Wt[d][j] = W[j][d]
    __shared__ float xT[128][129];   // xT[d][node_local]
    int tid = threadIdx.x;
    // stage W transposed (coalesced row reads, conflict-free scalar writes)
    {
        int r = tid >> 5;            // 0..7
        int c = (tid & 31) * 4;
        for (int rr = r; rr < 128; rr += 8) {
            float4 wv = *(const float4*)(W + rr * 128 + c);
            Wt[c + 0][rr] = wv.x;
            Wt[c + 1][rr] = wv.y;
            Wt[c + 2][rr] = wv.z;
            Wt[c + 3][rr] = wv.w;
        }
    }
    int fblk = (tid & 15) * 8;       // 8 output features
    int nblk = (tid >> 4) * 8;       // 8 nodes (local)
    float bv[8];
#pragma unroll
    for (int f = 0; f < 8; f++) bv[f] = b[fblk + f];

    int nchunks = (N + 127) / 128;
    for (int ch = blockIdx.x; ch < nchunks; ch += gridDim.x) {
        int base = ch * 128;
        __syncthreads();
        // stage x chunk transposed
        {
            int r = tid >> 5;
            int c = (tid & 31) * 4;
            for (int rr = r; rr < 128; rr += 8) {
                int nd = base + rr;
                float4 xv = (nd < N) ? *(const float4*)(x + (size_t)nd * DIM + c)
                                     : make_float4(0.f, 0.f, 0.f, 0.f);
                xT[c + 0][rr] = xv.x;
                xT[c + 1][rr] = xv.y;
                xT[c + 2][rr] = xv.z;
                xT[c + 3][rr] = xv.w;
            }
        }
        __syncthreads();
        float acc[8][8];
#pragma unroll
        for (int i = 0; i < 8; i++)
#pragma unroll
            for (int f = 0; f < 8; f++) acc[i][f] = bv[f];
        for (int d = 0; d < 128; d++) {
            float4 xa = *(const float4*)&xT[d][nblk];
            float4 xb = *(const float4*)&xT[d][nblk + 4];
            float4 wa = *(const float4*)&Wt[d][fblk];
            float4 wb = *(const float4*)&Wt[d][fblk + 4];
            float xv[8] = {xa.x, xa.y, xa.z, xa.w, xb.x, xb.y, xb.z, xb.w};
            float wv[8] = {wa.x, wa.y, wa.z, wa.w, wb.x, wb.y, wb.z, wb.w};
#pragma unroll
            for (int i = 0; i < 8; i++)
#pragma unroll
                for (int f = 0; f < 8; f++) acc[i][f] += xv[i] * wv[f];
        }
        for (int i = 0; i < 8; i++) {
            int nd = base + nblk + i;
            if (nd < N) {
                float* yp = y + (size_t)nd * DIM + fblk;
                *(float4*)yp = make_float4(acc[i][0], acc[i][1], acc[i][2], acc[i][3]);
                *(float4*)(yp + 4) = make_float4(acc[i][4], acc[i][5], acc[i][6], acc[i][7]);
            }
        }
    }
}

// ---------------- count: deg[src] += 1 (float), cnt[dst] += 1 (int) ----------------
__global__ void count_kernel(const int* __restrict__ src, const int* __restrict__ dst,
                             const float* __restrict__ valid,
                             float* __restrict__ degf, int* __restrict__ cnt) {
    int e = blockIdx.x * blockDim.x + threadIdx.x;
    if (e < ETOT) {
        if (valid[e] != 0.f) {
            atomicAdd(&degf[src[e]], 1.0f);
            atomicAdd(&cnt[dst[e]], 1);
        }
    }
}

// ---------------- per-graph exclusive scan: node buckets inside graph region ----------------
// one block per graph, 1024 threads; graph g's edges live in [g*EPG, (g+1)*EPG)
__global__ __launch_bounds__(1024) void scan_graph_kernel(const int* __restrict__ cnt,
                            int* __restrict__ eoff, int* __restrict__ cursor, int n) {
    __shared__ int sh[1024];
    int g = blockIdx.x, t = threadIdx.x;
    int v = (t < n) ? cnt[g * n + t] : 0;
    sh[t] = v;
    __syncthreads();
    for (int off = 1; off < 1024; off <<= 1) {
        int u = (t >= off) ? sh[t - off] : 0;
        __syncthreads();
        sh[t] += u;
        __syncthreads();
    }
    if (t < n) {
        int pos = g * EPG + sh[t] - v;   // exclusive prefix within graph region
        eoff[g * n + t] = pos;
        cursor[g * n + t] = pos;
    }
}

// ---------------- scatter valid edges into CSR by dst ----------------
__global__ void scatter_kernel(const int* __restrict__ src, const int* __restrict__ dst,
                               const float* __restrict__ valid,
                               int* __restrict__ cursor, int* __restrict__ esrc_s) {
    int e = blockIdx.x * blockDim.x + threadIdx.x;
    if (e < ETOT) {
        if (valid[e] != 0.f) {
            int pos = atomicAdd(&cursor[dst[e]], 1);
            esrc_s[pos] = src[e];
        }
    }
}

// ---------------- fused aggregate + self + relu + score ----------------
__global__ void fused_agg_kernel(const float* __restrict__ xL, const int* __restrict__ esrc,
                                 const int* __restrict__ eoff, const int* __restrict__ cnt,
                                 const float* __restrict__ degf,
                                 const float* __restrict__ pw, const float* __restrict__ invn,
                                 float* __restrict__ xA, float* __restrict__ score, int N) {
    int t = threadIdx.x;
    int n = blockIdx.x * 8 + (t >> 5);
    int lane = t & 31;
    if (n >= N) return;
    float dn = degf[n] + 1.0f;
    float dsn = rsqrtf(dn);
    const float4* selfp = (const float4*)(xL + (size_t)n * DIM);
    float4 sv = selfp[lane];
    float inv_dn = 1.0f / dn;
    float4 acc = make_float4(sv.x * inv_dn, sv.y * inv_dn, sv.z * inv_dn, sv.w * inv_dn);
    int s0 = eoff[n], s1 = s0 + cnt[n];
    for (int j = s0; j < s1; j++) {
        int s = esrc[j];
        float norm = dsn * rsqrtf(degf[s] + 1.0f);
        const float4* xp = (const float4*)(xL + (size_t)s * DIM);
        float4 xv = xp[lane];
        acc.x += norm * xv.x;
        acc.y += norm * xv.y;
        acc.z += norm * xv.z;
        acc.w += norm * xv.w;
    }
    acc.x = fmaxf(acc.x, 0.f);
    acc.y = fmaxf(acc.y, 0.f);
    acc.z = fmaxf(acc.z, 0.f);
    acc.w = fmaxf(acc.w, 0.f);
    ((float4*)(xA + (size_t)n * DIM))[lane] = acc;
    const float4* pwp = (const float4*)pw;
    float4 pv = pwp[lane];
    float dot = acc.x * pv.x + acc.y * pv.y + acc.z * pv.z + acc.w * pv.w;
    for (int off = 16; off >= 1; off >>= 1) dot += __shfl_xor(dot, off, 32);
    if (lane == 0) score[n] = tanhf(dot * invn[0]);
}

// ---------------- pool weight inverse norm ----------------
__global__ void invnorm_kernel(const float* __restrict__ pw, float* __restrict__ invn) {
    __shared__ float sh[DIM];
    int t = threadIdx.x;
    float v = pw[t];
    sh[t] = v * v;
    __syncthreads();
    for (int s = 64; s > 0; s >>= 1) {
        if (t < s) sh[t] += sh[t + s];
        __syncthreads();
    }
    if (t == 0) invn[0] = rsqrtf(sh[0]);
}

// ---------------- per-graph bitonic top-k sort ----------------
__global__ void topk_sort_kernel(const float* __restrict__ sc, int n,
                                 float* __restrict__ skey_out, int* __restrict__ sidx_out) {
    __shared__ float key[1024];
    __shared__ int idx[1024];
    int g = blockIdx.x;
    for (int i = threadIdx.x; i < 1024; i += blockDim.x) {
        if (i < n) { key[i] = sc[g * n + i]; idx[i] = i; }
        else       { key[i] = -2.0f;         idx[i] = i; }
    }
    __syncthreads();
    for (unsigned ksz = 2; ksz <= 1024; ksz <<= 1) {
        for (unsigned j = ksz >> 1; j > 0; j >>= 1) {
            for (unsigned i = threadIdx.x; i < 1024; i += blockDim.x) {
                unsigned ixj = i ^ j;
                if (ixj > i) {
                    float ka = key[i], kb = key[ixj];
                    int ia = idx[i], ib = idx[ixj];
                    bool aLess = (ka > kb) || (ka == kb && ia < ib);
                    bool up = ((i & ksz) == 0);
                    bool sw = up ? !aLess : aLess;
                    if (sw) { key[i] = kb; key[ixj] = ka; idx[i] = ib; idx[ixj] = ia; }
                }
            }
            __syncthreads();
        }
    }
    for (int i = threadIdx.x; i < 1024; i += blockDim.x) {
        skey_out[g * 1024 + i] = key[i];
        sidx_out[g * 1024 + i] = idx[i];
    }
}

__global__ void topk_finish_kernel(const int* __restrict__ sidx, int* __restrict__ new_id,
                                   int n, int k) {
    int g = blockIdx.x;
    int t = threadIdx.x;
    if (t < k) new_id[g * n + sidx[g * 1024 + t]] = g * k + t;
}

__global__ void gather_kernel(const float* __restrict__ x, const float* __restrict__ skey,
                              const int* __restrict__ sidx, float* __restrict__ xn,
                              int n, int k) {
    int gj = blockIdx.x;
    int g = gj / k;
    int j = gj - g * k;
    int local = sidx[g * 1024 + j];
    float sval = skey[g * 1024 + j];
    xn[(size_t)gj * DIM + threadIdx.x] = x[((size_t)g * n + local) * DIM + threadIdx.x] * sval;
}

__global__ void remap_kernel(int* __restrict__ src, int* __restrict__ dst,
                             float* __restrict__ valid, const int* __restrict__ new_id) {
    int e = blockIdx.x * blockDim.x + threadIdx.x;
    if (e < ETOT) {
        int s = new_id[src[e]];
        int d = new_id[dst[e]];
        float v = valid[e];
        v = (s >= 0 && d >= 0) ? v : 0.f;
        src[e] = s >= 0 ? s : 0;
        dst[e] = d >= 0 ? d : 0;
        valid[e] = v;
    }
}

// ---------------- readout: h[g] += [max_k ; mean_k], wide version ----------------
// 1024 threads per graph: 32 j-chunks x 32 feature-float4 lanes, LDS tree reduce.
__global__ __launch_bounds__(1024) void readout_kernel(const float* __restrict__ xn,
                                                       float* __restrict__ h, int k) {
    __shared__ float4 smax[32][33];
    __shared__ float4 ssum[32][33];
    int g = blockIdx.x;
    int t = threadIdx.x;
    int lane4 = t & 31;    // feature group (4 floats)
    int ch = t >> 5;       // j-chunk 0..31
    const float4* base = (const float4*)(xn + (size_t)g * k * DIM);
    float4 mx = make_float4(-INFINITY, -INFINITY, -INFINITY, -INFINITY);
    float4 sm = make_float4(0.f, 0.f, 0.f, 0.f);
    for (int j = ch; j < k; j += 32) {
        float4 v = base[j * 32 + lane4];
        mx.x = fmaxf(mx.x, v.x); mx.y = fmaxf(mx.y, v.y);
        mx.z = fmaxf(mx.z, v.z); mx.w = fmaxf(mx.w, v.w);
        sm.x += v.x; sm.y += v.y; sm.z += v.z; sm.w += v.w;
    }
    smax[ch][lane4] = mx;
    ssum[ch][lane4] = sm;
    __syncthreads();
    for (int s = 16; s >= 1; s >>= 1) {
        if (ch < s) {
            float4 a = smax[ch][lane4], bb = smax[ch + s][lane4];
            a.x = fmaxf(a.x, bb.x); a.y = fmaxf(a.y, bb.y);
            a.z = fmaxf(a.z, bb.z); a.w = fmaxf(a.w, bb.w);
            smax[ch][lane4] = a;
            float4 c = ssum[ch][lane4], d = ssum[ch + s][lane4];
            c.x += d.x; c.y += d.y; c.z += d.z; c.w += d.w;
            ssum[ch][lane4] = c;
        }
        __syncthreads();
    }
    if (ch == 0) {
        float4 m = smax[0][lane4];
        float4 s4 = ssum[0][lane4];
        float invk = 1.0f / (float)k;
        int f0 = lane4 * 4;
        float* hp = h + g * 256;
        hp[f0 + 0] += m.x; hp[f0 + 1] += m.y; hp[f0 + 2] += m.z; hp[f0 + 3] += m.w;
        hp[128 + f0 + 0] += s4.x * invk; hp[128 + f0 + 1] += s4.y * invk;
        hp[128 + f0 + 2] += s4.z * invk; hp[128 + f0 + 3] += s4.w * invk;
    }
}

__global__ void head_kernel(const float* __restrict__ h,
                            const float* __restrict__ l1w, const float* __restrict__ l1b,
                            const float* __restrict__ l2w, const float* __restrict__ l2b,
                            const float* __restrict__ l3w, const float* __restrict__ l3b,
                            float* __restrict__ out) {
    __shared__ float hr[256];
    __shared__ float h1[128];
    __shared__ float h2[64];
    __shared__ float lz[2];
    int g = blockIdx.x, t = threadIdx.x;
    hr[t] = h[g * 256 + t];
    hr[t + 128] = h[g * 256 + 128 + t];
    __syncthreads();
    float acc = l1b[t];
    for (int d = 0; d < 256; d++) acc += hr[d] * l1w[t * 256 + d];
    h1[t] = fmaxf(acc, 0.f);
    __syncthreads();
    if (t < 64) {
        float a2 = l2b[t];
        for (int d = 0; d < 128; d++) a2 += h1[d] * l2w[t * 128 + d];
        h2[t] = fmaxf(a2, 0.f);
    }
    __syncthreads();
    if (t < 2) {
        float a3 = l3b[t];
        for (int d = 0; d < 64; d++) a3 += h2[d] * l3w[t * 64 + d];
        lz[t] = a3;
    }
    __syncthreads();
    if (t < 2) {
        float z0 = lz[0], z1 = lz[1];
        float m = fmaxf(z0, z1);
        float lse = m + logf(expf(z0 - m) + expf(z1 - m));
        out[g * 2 + t] = lz[t] - lse;
    }
}

extern "C" void kernel_launch(void* const* d_in, const int* in_sizes, int n_in,
                              void* d_out, int out_size, void* d_ws, size_t ws_size,
                              hipStream_t stream) {
    const float* x_in = (const float*)d_in[0];
    const int* edge_index = (const int*)d_in[1];
    const float *cw[5], *cb[5], *pw[5];
    for (int i = 0; i < 5; i++) {
        cw[i] = (const float*)d_in[3 + 3 * i];
        cb[i] = (const float*)d_in[4 + 3 * i];
        pw[i] = (const float*)d_in[5 + 3 * i];
    }
    const float* l1w = (const float*)d_in[18];
    const float* l1b = (const float*)d_in[19];
    const float* l2w = (const float*)d_in[20];
    const float* l2b = (const float*)d_in[21];
    const float* l3w = (const float*)d_in[22];
    const float* l3b = (const float*)d_in[23];
    float* out = (float*)d_out;

    char* w = (char*)d_ws;
    float* xA    = (float*)w; w += (size_t)65536 * DIM * 4;
    float* xB    = (float*)w; w += (size_t)65536 * DIM * 4;
    float* xL    = (float*)w; w += (size_t)65536 * DIM * 4;
    int*   src   = (int*)w;   w += (size_t)ETOT * 4;
    int*   dst   = (int*)w;   w += (size_t)ETOT * 4;
    float* valid = (float*)w; w += (size_t)ETOT * 4;
    int*   esrc_s= (int*)w;   w += (size_t)ETOT * 4;
    float* deg   = (float*)w; w += (size_t)65536 * 4;
    int*   cnt   = (int*)w;   w += (size_t)65536 * 4;
    int*   eoff  = (int*)w;   w += (size_t)(65536 + 1) * 4;
    int*   cursor= (int*)w;   w += (size_t)65536 * 4;
    float* score = (float*)w; w += (size_t)65536 * 4;
    float* skey  = (float*)w; w += (size_t)NB * 1024 * 4;
    int*   sidx  = (int*)w;   w += (size_t)NB * 1024 * 4;
    int*   newid = (int*)w;   w += (size_t)65536 * 4;
    float* hsum  = (float*)w; w += (size_t)NB * 256 * 4;
    float* invn  = (float*)w; w += 4;

    hipMemcpyAsync(src, edge_index, (size_t)ETOT * 4, hipMemcpyDeviceToDevice, stream);
    hipMemcpyAsync(dst, edge_index + ETOT, (size_t)ETOT * 4, hipMemcpyDeviceToDevice, stream);
    fill_ones_kernel<<<ETOT / 256, 256, 0, stream>>>(valid, ETOT);
    hipMemsetAsync(hsum, 0, (size_t)NB * 256 * 4, stream);

    const float* xin = x_in;
    for (int i = 0; i < 5; i++) {
        int n = NS_H[i], k = NS_H[i + 1];
        int N = NB * n, K = NB * k;

        linear_kernel<<<256, 256, 0, stream>>>(xin, cw[i], cb[i], xL, N);

        hipMemsetAsync(deg, 0, (size_t)N * 4, stream);
        hipMemsetAsync(cnt, 0, (size_t)N * 4, stream);
        count_kernel<<<ETOT / 256, 256, 0, stream>>>(src, dst, valid, deg, cnt);
        scan_graph_kernel<<<NB, 1024, 0, stream>>>(cnt, eoff, cursor, n);
        scatter_kernel<<<ETOT / 256, 256, 0, stream>>>(src, dst, valid, cursor, esrc_s);

        invnorm_kernel<<<1, 128, 0, stream>>>(pw[i], invn);
        fused_agg_kernel<<<(N + 7) / 8, 256, 0, stream>>>(xL, esrc_s, eoff, cnt, deg, pw[i],
                                                          invn, xA, score, N);

        topk_sort_kernel<<<NB, 512, 0, stream>>>(score, n, skey, sidx);
        hipMemsetAsync(newid, 0xFF, (size_t)N * 4, stream);
        topk_finish_kernel<<<NB, 1024, 0, stream>>>(sidx, newid, n, k);
        gather_kernel<<<K, 128, 0, stream>>>(xA, skey, sidx, xB, n, k);
        remap_kernel<<<ETOT / 256, 256, 0, stream>>>(src, dst, valid, newid);
        readout_kernel<<<NB, 1024, 0, stream>>>(xB, hsum, k);

        xin = xB;
    }

    head_kernel<<<NB, 128, 0, stream>>>(hsum, l1w, l1b, l2w, l2b, l3w, l3b, out);
}

// Round 4
// 1082.029 us; speedup vs baseline: 5.6242x; 1.1490x over previous
//
#include <hip/hip_runtime.h>
#include <math.h>

#define NB 64
#define DIM 128
#define ETOT 1048576
#define EPG 16384   // edges-per-graph region (ETOT / NB)

static const int NS_H[6] = {1024, 820, 656, 525, 420, 336};

// ---------------- initial degree/count (all edges valid) ----------------
__global__ void init_count_kernel(const int* __restrict__ src, const int* __restrict__ dst,
                                  float* __restrict__ deg, int* __restrict__ cnt) {
    int e = blockIdx.x * blockDim.x + threadIdx.x;
    if (e < ETOT) {
        atomicAdd(&deg[src[e]], 1.0f);
        atomicAdd(&cnt[dst[e]], 1);
    }
}

// ---------------- linear: y = x @ W.T + b  (LDS-staged tiled fp32 GEMM) ----------------
__global__ __launch_bounds__(256) void linear_kernel(const float* __restrict__ x,
                              const float* __restrict__ W, const float* __restrict__ b,
                              float* __restrict__ y, int N) {
    __shared__ float Wt[128][129];
    __shared__ float xT[128][129];
    int tid = threadIdx.x;
    {
        int r = tid >> 5;
        int c = (tid & 31) * 4;
        for (int rr = r; rr < 128; rr += 8) {
            float4 wv = *(const float4*)(W + rr * 128 + c);
            Wt[c + 0][rr] = wv.x;
            Wt[c + 1][rr] = wv.y;
            Wt[c + 2][rr] = wv.z;
            Wt[c + 3][rr] = wv.w;
        }
    }
    int fblk = (tid & 15) * 8;
    int nblk = (tid >> 4) * 8;
    float bv[8];
#pragma unroll
    for (int f = 0; f < 8; f++) bv[f] = b[fblk + f];

    int nchunks = (N + 127) / 128;
    for (int ch = blockIdx.x; ch < nchunks; ch += gridDim.x) {
        int base = ch * 128;
        __syncthreads();
        {
            int r = tid >> 5;
            int c = (tid & 31) * 4;
            for (int rr = r; rr < 128; rr += 8) {
                int nd = base + rr;
                float4 xv = (nd < N) ? *(const float4*)(x + (size_t)nd * DIM + c)
                                     : make_float4(0.f, 0.f, 0.f, 0.f);
                xT[c + 0][rr] = xv.x;
                xT[c + 1][rr] = xv.y;
                xT[c + 2][rr] = xv.z;
                xT[c + 3][rr] = xv.w;
            }
        }
        __syncthreads();
        float acc[8][8];
#pragma unroll
        for (int i = 0; i < 8; i++)
#pragma unroll
            for (int f = 0; f < 8; f++) acc[i][f] = bv[f];
        for (int d = 0; d < 128; d++) {
            float4 xa = *(const float4*)&xT[d][nblk];
            float4 xb = *(const float4*)&xT[d][nblk + 4];
            float4 wa = *(const float4*)&Wt[d][fblk];
            float4 wb = *(const float4*)&Wt[d][fblk + 4];
            float xv[8] = {xa.x, xa.y, xa.z, xa.w, xb.x, xb.y, xb.z, xb.w};
            float wv[8] = {wa.x, wa.y, wa.z, wa.w, wb.x, wb.y, wb.z, wb.w};
#pragma unroll
            for (int i = 0; i < 8; i++)
#pragma unroll
                for (int f = 0; f < 8; f++) acc[i][f] += xv[i] * wv[f];
        }
        for (int i = 0; i < 8; i++) {
            int nd = base + nblk + i;
            if (nd < N) {
                float* yp = y + (size_t)nd * DIM + fblk;
                *(float4*)yp = make_float4(acc[i][0], acc[i][1], acc[i][2], acc[i][3]);
                *(float4*)(yp + 4) = make_float4(acc[i][4], acc[i][5], acc[i][6], acc[i][7]);
            }
        }
    }
}

// ---------------- per-graph scan + dinv precompute + (block0) pw invnorm ----------------
__global__ __launch_bounds__(1024) void scan_graph_kernel(const int* __restrict__ cnt,
                            const float* __restrict__ deg, float* __restrict__ dinv,
                            int* __restrict__ eoff, int* __restrict__ cursor, int n,
                            const float* __restrict__ pw, float* __restrict__ invn) {
    __shared__ int sh[1024];
    __shared__ float shf[128];
    int g = blockIdx.x, t = threadIdx.x;
    int v = (t < n) ? cnt[g * n + t] : 0;
    sh[t] = v;
    __syncthreads();
    for (int off = 1; off < 1024; off <<= 1) {
        int u = (t >= off) ? sh[t - off] : 0;
        __syncthreads();
        sh[t] += u;
        __syncthreads();
    }
    if (t < n) {
        int pos = g * EPG + sh[t] - v;
        eoff[g * n + t] = pos;
        cursor[g * n + t] = pos;
        dinv[g * n + t] = rsqrtf(deg[g * n + t] + 1.0f);
    }
    if (g == 0) {
        if (t < 128) shf[t] = pw[t] * pw[t];
        __syncthreads();
        for (int s = 64; s > 0; s >>= 1) {
            if (t < s) shf[t] += shf[t + s];
            __syncthreads();
        }
        if (t == 0) invn[0] = rsqrtf(shf[0]);
    }
}

// ---------------- scatter valid edges into CSR by dst ----------------
__global__ void scatter_kernel(const int* __restrict__ src, const int* __restrict__ dst,
                               int* __restrict__ cursor, int* __restrict__ esrc_s) {
    int e = blockIdx.x * blockDim.x + threadIdx.x;
    if (e < ETOT) {
        int s = src[e];
        if (s >= 0) {
            int pos = atomicAdd(&cursor[dst[e]], 1);
            esrc_s[pos] = s;
        }
    }
}

// ---------------- fused aggregate + self + relu + score (XCD-swizzled) ----------------
// grid = NB * gpb blocks; block b -> graph b % NB (so graph g pins to XCD g%8).
__global__ void fused_agg_kernel(const float* __restrict__ xL, const int* __restrict__ esrc,
                                 const int* __restrict__ eoff, const int* __restrict__ cnt,
                                 const float* __restrict__ dinv,
                                 const float* __restrict__ pw, const float* __restrict__ invn,
                                 float* __restrict__ xA, float* __restrict__ score, int n) {
    int t = threadIdx.x;
    int g = blockIdx.x % NB;
    int chunk = blockIdx.x / NB;
    int ln = chunk * 8 + (t >> 5);
    if (ln >= n) return;
    int node = g * n + ln;
    int lane = t & 31;
    float dsn = dinv[node];
    const float4* selfp = (const float4*)(xL + (size_t)node * DIM);
    float4 sv = selfp[lane];
    float inv_dn = dsn * dsn;
    float4 acc = make_float4(sv.x * inv_dn, sv.y * inv_dn, sv.z * inv_dn, sv.w * inv_dn);
    int s0 = eoff[node], s1 = s0 + cnt[node];
    for (int j = s0; j < s1; j++) {
        int s = esrc[j];
        float norm = dsn * dinv[s];
        const float4* xp = (const float4*)(xL + (size_t)s * DIM);
        float4 xv = xp[lane];
        acc.x += norm * xv.x;
        acc.y += norm * xv.y;
        acc.z += norm * xv.z;
        acc.w += norm * xv.w;
    }
    acc.x = fmaxf(acc.x, 0.f);
    acc.y = fmaxf(acc.y, 0.f);
    acc.z = fmaxf(acc.z, 0.f);
    acc.w = fmaxf(acc.w, 0.f);
    ((float4*)(xA + (size_t)node * DIM))[lane] = acc;
    const float4* pwp = (const float4*)pw;
    float4 pv = pwp[lane];
    float dot = acc.x * pv.x + acc.y * pv.y + acc.z * pv.z + acc.w * pv.w;
    for (int off = 16; off >= 1; off >>= 1) dot += __shfl_xor(dot, off, 32);
    if (lane == 0) score[node] = tanhf(dot * invn[0]);
}

// ---------------- bitonic sort + newid build + next-layer deg/cnt zero ----------------
__global__ __launch_bounds__(512) void topk_sort_kernel(const float* __restrict__ sc, int n,
                                 int k, float* __restrict__ skey_out, int* __restrict__ sidx_out,
                                 int* __restrict__ new_id, float* __restrict__ degN,
                                 int* __restrict__ cntN) {
    __shared__ float key[1024];
    __shared__ int idx[1024];
    int g = blockIdx.x;
    for (int i = threadIdx.x; i < 1024; i += blockDim.x) {
        if (i < n) { key[i] = sc[g * n + i]; idx[i] = i; }
        else       { key[i] = -2.0f;         idx[i] = i; }
    }
    // zero next-layer deg/cnt while sort data loads
    for (int i = threadIdx.x; i < k; i += blockDim.x) {
        degN[g * k + i] = 0.f;
        cntN[g * k + i] = 0;
    }
    __syncthreads();
    for (unsigned ksz = 2; ksz <= 1024; ksz <<= 1) {
        for (unsigned j = ksz >> 1; j > 0; j >>= 1) {
            for (unsigned i = threadIdx.x; i < 1024; i += blockDim.x) {
                unsigned ixj = i ^ j;
                if (ixj > i) {
                    float ka = key[i], kb = key[ixj];
                    int ia = idx[i], ib = idx[ixj];
                    bool aLess = (ka > kb) || (ka == kb && ia < ib);
                    bool up = ((i & ksz) == 0);
                    bool sw = up ? !aLess : aLess;
                    if (sw) { key[i] = kb; key[ixj] = ka; idx[i] = ib; idx[ixj] = ia; }
                }
            }
            __syncthreads();
        }
    }
    for (int i = threadIdx.x; i < 1024; i += blockDim.x) {
        skey_out[g * 1024 + i] = key[i];
        sidx_out[g * 1024 + i] = idx[i];
        if (i < n) new_id[g * n + idx[i]] = (i < k) ? (g * k + i) : -1;
    }
}

// ---------------- fused gather (xn = x[perm]*s) + readout max/mean ----------------
__global__ __launch_bounds__(1024) void gather_readout_kernel(const float* __restrict__ xA,
                              const float* __restrict__ skey, const int* __restrict__ sidx,
                              float* __restrict__ xn, float* __restrict__ h, int n, int k) {
    __shared__ float4 smax[32][33];
    __shared__ float4 ssum[32][33];
    int g = blockIdx.x;
    int t = threadIdx.x;
    int lane4 = t & 31;
    int ch = t >> 5;
    float4 mx = make_float4(-INFINITY, -INFINITY, -INFINITY, -INFINITY);
    float4 sm = make_float4(0.f, 0.f, 0.f, 0.f);
    for (int j = ch; j < k; j += 32) {
        int row = sidx[g * 1024 + j];
        float sval = skey[g * 1024 + j];
        float4 v = ((const float4*)(xA + ((size_t)g * n + row) * DIM))[lane4];
        v.x *= sval; v.y *= sval; v.z *= sval; v.w *= sval;
        ((float4*)(xn + ((size_t)g * k + j) * DIM))[lane4] = v;
        mx.x = fmaxf(mx.x, v.x); mx.y = fmaxf(mx.y, v.y);
        mx.z = fmaxf(mx.z, v.z); mx.w = fmaxf(mx.w, v.w);
        sm.x += v.x; sm.y += v.y; sm.z += v.z; sm.w += v.w;
    }
    smax[ch][lane4] = mx;
    ssum[ch][lane4] = sm;
    __syncthreads();
    for (int s = 16; s >= 1; s >>= 1) {
        if (ch < s) {
            float4 a = smax[ch][lane4], bb = smax[ch + s][lane4];
            a.x = fmaxf(a.x, bb.x); a.y = fmaxf(a.y, bb.y);
            a.z = fmaxf(a.z, bb.z); a.w = fmaxf(a.w, bb.w);
            smax[ch][lane4] = a;
            float4 c = ssum[ch][lane4], d = ssum[ch + s][lane4];
            c.x += d.x; c.y += d.y; c.z += d.z; c.w += d.w;
            ssum[ch][lane4] = c;
        }
        __syncthreads();
    }
    if (ch == 0) {
        float4 m = smax[0][lane4];
        float4 s4 = ssum[0][lane4];
        float invk = 1.0f / (float)k;
        int f0 = lane4 * 4;
        float* hp = h + g * 256;
        hp[f0 + 0] += m.x; hp[f0 + 1] += m.y; hp[f0 + 2] += m.z; hp[f0 + 3] += m.w;
        hp[128 + f0 + 0] += s4.x * invk; hp[128 + f0 + 1] += s4.y * invk;
        hp[128 + f0 + 2] += s4.z * invk; hp[128 + f0 + 3] += s4.w * invk;
    }
}

// ---------------- remap edges + count next-layer deg/cnt ----------------
__global__ void remap_count_kernel(int* __restrict__ src, int* __restrict__ dst,
                                   const int* __restrict__ new_id,
                                   float* __restrict__ deg, int* __restrict__ cnt) {
    int e = blockIdx.x * blockDim.x + threadIdx.x;
    if (e < ETOT) {
        int s = src[e];
        if (s < 0) return;  // already dead, stays dead
        int d = dst[e];
        int s2 = new_id[s];
        int d2 = new_id[d];
        if (s2 >= 0 && d2 >= 0) {
            src[e] = s2;
            dst[e] = d2;
            atomicAdd(&deg[s2], 1.0f);
            atomicAdd(&cnt[d2], 1);
        } else {
            src[e] = -1;
            dst[e] = -1;
        }
    }
}

__global__ void head_kernel(const float* __restrict__ h,
                            const float* __restrict__ l1w, const float* __restrict__ l1b,
                            const float* __restrict__ l2w, const float* __restrict__ l2b,
                            const float* __restrict__ l3w, const float* __restrict__ l3b,
                            float* __restrict__ out) {
    __shared__ float hr[256];
    __shared__ float h1[128];
    __shared__ float h2[64];
    __shared__ float lz[2];
    int g = blockIdx.x, t = threadIdx.x;
    hr[t] = h[g * 256 + t];
    hr[t + 128] = h[g * 256 + 128 + t];
    __syncthreads();
    float acc = l1b[t];
    for (int d = 0; d < 256; d++) acc += hr[d] * l1w[t * 256 + d];
    h1[t] = fmaxf(acc, 0.f);
    __syncthreads();
    if (t < 64) {
        float a2 = l2b[t];
        for (int d = 0; d < 128; d++) a2 += h1[d] * l2w[t * 128 + d];
        h2[t] = fmaxf(a2, 0.f);
    }
    __syncthreads();
    if (t < 2) {
        float a3 = l3b[t];
        for (int d = 0; d < 64; d++) a3 += h2[d] * l3w[t * 64 + d];
        lz[t] = a3;
    }
    __syncthreads();
    if (t < 2) {
        float z0 = lz[0], z1 = lz[1];
        float m = fmaxf(z0, z1);
        float lse = m + logf(expf(z0 - m) + expf(z1 - m));
        out[g * 2 + t] = lz[t] - lse;
    }
}

extern "C" void kernel_launch(void* const* d_in, const int* in_sizes, int n_in,
                              void* d_out, int out_size, void* d_ws, size_t ws_size,
                              hipStream_t stream) {
    const float* x_in = (const float*)d_in[0];
    const int* edge_index = (const int*)d_in[1];
    const float *cw[5], *cb[5], *pw[5];
    for (int i = 0; i < 5; i++) {
        cw[i] = (const float*)d_in[3 + 3 * i];
        cb[i] = (const float*)d_in[4 + 3 * i];
        pw[i] = (const float*)d_in[5 + 3 * i];
    }
    const float* l1w = (const float*)d_in[18];
    const float* l1b = (const float*)d_in[19];
    const float* l2w = (const float*)d_in[20];
    const float* l2b = (const float*)d_in[21];
    const float* l3w = (const float*)d_in[22];
    const float* l3b = (const float*)d_in[23];
    float* out = (float*)d_out;

    char* w = (char*)d_ws;
    float* xA    = (float*)w; w += (size_t)65536 * DIM * 4;
    float* xB    = (float*)w; w += (size_t)65536 * DIM * 4;
    float* xL    = (float*)w; w += (size_t)65536 * DIM * 4;
    int*   src   = (int*)w;   w += (size_t)ETOT * 4;
    int*   dst   = (int*)w;   w += (size_t)ETOT * 4;
    int*   esrc_s= (int*)w;   w += (size_t)ETOT * 4;
    float* deg   = (float*)w; w += (size_t)65536 * 4;
    int*   cnt   = (int*)w;   w += (size_t)65536 * 4;
    int*   eoff  = (int*)w;   w += (size_t)65536 * 4;
    int*   cursor= (int*)w;   w += (size_t)65536 * 4;
    float* dinv  = (float*)w; w += (size_t)65536 * 4;
    float* score = (float*)w; w += (size_t)65536 * 4;
    float* skey  = (float*)w; w += (size_t)NB * 1024 * 4;
    int*   sidx  = (int*)w;   w += (size_t)NB * 1024 * 4;
    int*   newid = (int*)w;   w += (size_t)65536 * 4;
    float* hsum  = (float*)w; w += (size_t)NB * 256 * 4;
    float* invn  = (float*)w; w += 4;

    hipMemcpyAsync(src, edge_index, (size_t)ETOT * 4, hipMemcpyDeviceToDevice, stream);
    hipMemcpyAsync(dst, edge_index + ETOT, (size_t)ETOT * 4, hipMemcpyDeviceToDevice, stream);
    hipMemsetAsync(deg, 0, (size_t)65536 * 4, stream);
    hipMemsetAsync(cnt, 0, (size_t)65536 * 4, stream);
    hipMemsetAsync(hsum, 0, (size_t)NB * 256 * 4, stream);
    init_count_kernel<<<ETOT / 256, 256, 0, stream>>>(src, dst, deg, cnt);

    const float* xin = x_in;
    for (int i = 0; i < 5; i++) {
        int n = NS_H[i], k = NS_H[i + 1];
        int N = NB * n;

        linear_kernel<<<256, 256, 0, stream>>>(xin, cw[i], cb[i], xL, N);
        scan_graph_kernel<<<NB, 1024, 0, stream>>>(cnt, deg, dinv, eoff, cursor, n, pw[i], invn);
        scatter_kernel<<<ETOT / 256, 256, 0, stream>>>(src, dst, cursor, esrc_s);

        int gpb = (n + 7) / 8;
        fused_agg_kernel<<<NB * gpb, 256, 0, stream>>>(xL, esrc_s, eoff, cnt, dinv, pw[i],
                                                       invn, xA, score, n);

        topk_sort_kernel<<<NB, 512, 0, stream>>>(score, n, k, skey, sidx, newid, deg, cnt);
        gather_readout_kernel<<<NB, 1024, 0, stream>>>(xA, skey, sidx, xB, hsum, n, k);
        if (i < 4)
            remap_count_kernel<<<ETOT / 256, 256, 0, stream>>>(src, dst, newid, deg, cnt);

        xin = xB;
    }

    head_kernel<<<NB, 128, 0, stream>>>(hsum, l1w, l1b, l2w, l2b, l3w, l3b, out);
}

// Round 5
// 1070.038 us; speedup vs baseline: 5.6872x; 1.0112x over previous
//
#include <hip/hip_runtime.h>
#include <math.h>

#define NB 64
#define DIM 128
#define ETOT 1048576
#define EPG 16384   // edges-per-graph region (ETOT / NB)
#define RSL 166     // LDS row stride (floats) for linear tiles

static const int NS_H[6] = {1024, 820, 656, 525, 420, 336};

// ---------------- initial degree/count (all edges valid) ----------------
__global__ void init_count_kernel(const int* __restrict__ src, const int* __restrict__ dst,
                                  float* __restrict__ deg, int* __restrict__ cnt) {
    int e = blockIdx.x * blockDim.x + threadIdx.x;
    if (e < ETOT) {
        atomicAdd(&deg[src[e]], 1.0f);
        atomicAdd(&cnt[dst[e]], 1);
    }
}

// ---------------- linear: y = x @ W.T + b ----------------
// 128 threads, tile 128 nodes x 128 feats, K sliced in 4x32.
// LDS layout: row d_local (stride RSL=166 floats); 16 fragments of 8 floats at
// stride 10 -> 16 distinct start banks (conflict-free reads), float2 (8B) aligned.
// Thread: nodes (tid&15)*8..+8, feats (tid>>4)*16..+16 -> acc[8][16].
__global__ __launch_bounds__(128) void linear_kernel(const float* __restrict__ x,
                              const float* __restrict__ W, const float* __restrict__ b,
                              float* __restrict__ y, int N) {
    __shared__ float xT[32 * RSL];
    __shared__ float Wt[32 * RSL];
    int tid = threadIdx.x;
    int base = blockIdx.x * 128;
    int ng = tid & 15;          // node fragment (8 nodes)
    int u  = tid >> 4;          // feat group: 16 feats = frags 2u, 2u+1
    float acc[8][16];
    {
        float bv[16];
#pragma unroll
        for (int f = 0; f < 16; f++) bv[f] = b[u * 16 + f];
#pragma unroll
        for (int i = 0; i < 8; i++)
#pragma unroll
            for (int f = 0; f < 16; f++) acc[i][f] = bv[f];
    }

    for (int kb = 0; kb < 4; kb++) {
        __syncthreads();
        // stage W-slice and x-slice: 128 rows x 32 d, coalesced float4 reads
        for (int q = 0; q < 8; q++) {
            int i = tid + 128 * q;       // 0..1023
            int r = i >> 3;              // row (feat or node-local) 0..127
            int dq = i & 7;              // which float4 of the 32-d slice
            int dd = dq * 4;
            int s = (r >> 3) * 10 + (r & 7);   // fragment-swizzled column
            float4 wv = *(const float4*)(W + r * 128 + kb * 32 + dd);
            Wt[(dd + 0) * RSL + s] = wv.x;
            Wt[(dd + 1) * RSL + s] = wv.y;
            Wt[(dd + 2) * RSL + s] = wv.z;
            Wt[(dd + 3) * RSL + s] = wv.w;
            int nd = base + r;
            float4 xv = (nd < N) ? *(const float4*)(x + (size_t)nd * DIM + kb * 32 + dd)
                                 : make_float4(0.f, 0.f, 0.f, 0.f);
            xT[(dd + 0) * RSL + s] = xv.x;
            xT[(dd + 1) * RSL + s] = xv.y;
            xT[(dd + 2) * RSL + s] = xv.z;
            xT[(dd + 3) * RSL + s] = xv.w;
        }
        __syncthreads();
#pragma unroll 2
        for (int d = 0; d < 32; d++) {
            const float* xr = &xT[d * RSL + ng * 10];
            float2 xv0 = *(const float2*)(xr + 0);
            float2 xv1 = *(const float2*)(xr + 2);
            float2 xv2 = *(const float2*)(xr + 4);
            float2 xv3 = *(const float2*)(xr + 6);
            const float* wr = &Wt[d * RSL + u * 20];
            float2 wv0 = *(const float2*)(wr + 0);
            float2 wv1 = *(const float2*)(wr + 2);
            float2 wv2 = *(const float2*)(wr + 4);
            float2 wv3 = *(const float2*)(wr + 6);
            float2 wv4 = *(const float2*)(wr + 10);
            float2 wv5 = *(const float2*)(wr + 12);
            float2 wv6 = *(const float2*)(wr + 14);
            float2 wv7 = *(const float2*)(wr + 16);
            float xs[8] = {xv0.x, xv0.y, xv1.x, xv1.y, xv2.x, xv2.y, xv3.x, xv3.y};
            float ws[16] = {wv0.x, wv0.y, wv1.x, wv1.y, wv2.x, wv2.y, wv3.x, wv3.y,
                            wv4.x, wv4.y, wv5.x, wv5.y, wv6.x, wv6.y, wv7.x, wv7.y};
#pragma unroll
            for (int i = 0; i < 8; i++)
#pragma unroll
                for (int f = 0; f < 16; f++)
                    acc[i][f] += xs[i] * ws[f];
        }
    }
#pragma unroll
    for (int i = 0; i < 8; i++) {
        int nd = base + ng * 8 + i;
        if (nd < N) {
            float* yp = y + (size_t)nd * DIM + u * 16;
            *(float4*)(yp + 0)  = make_float4(acc[i][0],  acc[i][1],  acc[i][2],  acc[i][3]);
            *(float4*)(yp + 4)  = make_float4(acc[i][4],  acc[i][5],  acc[i][6],  acc[i][7]);
            *(float4*)(yp + 8)  = make_float4(acc[i][8],  acc[i][9],  acc[i][10], acc[i][11]);
            *(float4*)(yp + 12) = make_float4(acc[i][12], acc[i][13], acc[i][14], acc[i][15]);
        }
    }
}

// ---------------- per-graph scan + dinv precompute + (block0) pw invnorm ----------------
__global__ __launch_bounds__(1024) void scan_graph_kernel(const int* __restrict__ cnt,
                            const float* __restrict__ deg, float* __restrict__ dinv,
                            int* __restrict__ eoff, int* __restrict__ cursor, int n,
                            const float* __restrict__ pw, float* __restrict__ invn) {
    __shared__ int sh[1024];
    __shared__ float shf[128];
    int g = blockIdx.x, t = threadIdx.x;
    int v = (t < n) ? cnt[g * n + t] : 0;
    sh[t] = v;
    __syncthreads();
    for (int off = 1; off < 1024; off <<= 1) {
        int u = (t >= off) ? sh[t - off] : 0;
        __syncthreads();
        sh[t] += u;
        __syncthreads();
    }
    if (t < n) {
        int pos = g * EPG + sh[t] - v;
        eoff[g * n + t] = pos;
        cursor[g * n + t] = pos;
        dinv[g * n + t] = rsqrtf(deg[g * n + t] + 1.0f);
    }
    if (g == 0) {
        if (t < 128) shf[t] = pw[t] * pw[t];
        __syncthreads();
        for (int s = 64; s > 0; s >>= 1) {
            if (t < s) shf[t] += shf[t + s];
            __syncthreads();
        }
        if (t == 0) invn[0] = rsqrtf(shf[0]);
    }
}

// ---------------- scatter valid edges into CSR by dst ----------------
__global__ void scatter_kernel(const int* __restrict__ src, const int* __restrict__ dst,
                               int* __restrict__ cursor, int* __restrict__ esrc_s) {
    int e = blockIdx.x * blockDim.x + threadIdx.x;
    if (e < ETOT) {
        int s = src[e];
        if (s >= 0) {
            int pos = atomicAdd(&cursor[dst[e]], 1);
            esrc_s[pos] = s;
        }
    }
}

// ---------------- fused aggregate + self + relu + score (XCD-swizzled) ----------------
__global__ void fused_agg_kernel(const float* __restrict__ xL, const int* __restrict__ esrc,
                                 const int* __restrict__ eoff, const int* __restrict__ cnt,
                                 const float* __restrict__ dinv,
                                 const float* __restrict__ pw, const float* __restrict__ invn,
                                 float* __restrict__ xA, float* __restrict__ score, int n) {
    int t = threadIdx.x;
    int g = blockIdx.x % NB;
    int chunk = blockIdx.x / NB;
    int ln = chunk * 8 + (t >> 5);
    if (ln >= n) return;
    int node = g * n + ln;
    int lane = t & 31;
    float dsn = dinv[node];
    const float4* selfp = (const float4*)(xL + (size_t)node * DIM);
    float4 sv = selfp[lane];
    float inv_dn = dsn * dsn;
    float4 acc = make_float4(sv.x * inv_dn, sv.y * inv_dn, sv.z * inv_dn, sv.w * inv_dn);
    int s0 = eoff[node], s1 = s0 + cnt[node];
    for (int j = s0; j < s1; j++) {
        int s = esrc[j];
        float norm = dsn * dinv[s];
        const float4* xp = (const float4*)(xL + (size_t)s * DIM);
        float4 xv = xp[lane];
        acc.x += norm * xv.x;
        acc.y += norm * xv.y;
        acc.z += norm * xv.z;
        acc.w += norm * xv.w;
    }
    acc.x = fmaxf(acc.x, 0.f);
    acc.y = fmaxf(acc.y, 0.f);
    acc.z = fmaxf(acc.z, 0.f);
    acc.w = fmaxf(acc.w, 0.f);
    ((float4*)(xA + (size_t)node * DIM))[lane] = acc;
    const float4* pwp = (const float4*)pw;
    float4 pv = pwp[lane];
    float dot = acc.x * pv.x + acc.y * pv.y + acc.z * pv.z + acc.w * pv.w;
    for (int off = 16; off >= 1; off >>= 1) dot += __shfl_xor(dot, off, 32);
    if (lane == 0) score[node] = tanhf(dot * invn[0]);
}

// ---------------- bitonic sort + newid build + next-layer deg/cnt zero ----------------
__global__ __launch_bounds__(512) void topk_sort_kernel(const float* __restrict__ sc, int n,
                                 int k, float* __restrict__ skey_out, int* __restrict__ sidx_out,
                                 int* __restrict__ new_id, float* __restrict__ degN,
                                 int* __restrict__ cntN) {
    __shared__ float key[1024];
    __shared__ int idx[1024];
    int g = blockIdx.x;
    for (int i = threadIdx.x; i < 1024; i += blockDim.x) {
        if (i < n) { key[i] = sc[g * n + i]; idx[i] = i; }
        else       { key[i] = -2.0f;         idx[i] = i; }
    }
    for (int i = threadIdx.x; i < k; i += blockDim.x) {
        degN[g * k + i] = 0.f;
        cntN[g * k + i] = 0;
    }
    __syncthreads();
    for (unsigned ksz = 2; ksz <= 1024; ksz <<= 1) {
        for (unsigned j = ksz >> 1; j > 0; j >>= 1) {
            for (unsigned i = threadIdx.x; i < 1024; i += blockDim.x) {
                unsigned ixj = i ^ j;
                if (ixj > i) {
                    float ka = key[i], kb = key[ixj];
                    int ia = idx[i], ib = idx[ixj];
                    bool aLess = (ka > kb) || (ka == kb && ia < ib);
                    bool up = ((i & ksz) == 0);
                    bool sw = up ? !aLess : aLess;
                    if (sw) { key[i] = kb; key[ixj] = ka; idx[i] = ib; idx[ixj] = ia; }
                }
            }
            __syncthreads();
        }
    }
    for (int i = threadIdx.x; i < 1024; i += blockDim.x) {
        skey_out[g * 1024 + i] = key[i];
        sidx_out[g * 1024 + i] = idx[i];
        if (i < n) new_id[g * n + idx[i]] = (i < k) ? (g * k + i) : -1;
    }
}

// ---------------- fused gather (xn = x[perm]*s) + readout max/mean ----------------
__global__ __launch_bounds__(1024) void gather_readout_kernel(const float* __restrict__ xA,
                              const float* __restrict__ skey, const int* __restrict__ sidx,
                              float* __restrict__ xn, float* __restrict__ h, int n, int k) {
    __shared__ float4 smax[32][33];
    __shared__ float4 ssum[32][33];
    int g = blockIdx.x;
    int t = threadIdx.x;
    int lane4 = t & 31;
    int ch = t >> 5;
    float4 mx = make_float4(-INFINITY, -INFINITY, -INFINITY, -INFINITY);
    float4 sm = make_float4(0.f, 0.f, 0.f, 0.f);
    for (int j = ch; j < k; j += 32) {
        int row = sidx[g * 1024 + j];
        float sval = skey[g * 1024 + j];
        float4 v = ((const float4*)(xA + ((size_t)g * n + row) * DIM))[lane4];
        v.x *= sval; v.y *= sval; v.z *= sval; v.w *= sval;
        ((float4*)(xn + ((size_t)g * k + j) * DIM))[lane4] = v;
        mx.x = fmaxf(mx.x, v.x); mx.y = fmaxf(mx.y, v.y);
        mx.z = fmaxf(mx.z, v.z); mx.w = fmaxf(mx.w, v.w);
        sm.x += v.x; sm.y += v.y; sm.z += v.z; sm.w += v.w;
    }
    smax[ch][lane4] = mx;
    ssum[ch][lane4] = sm;
    __syncthreads();
    for (int s = 16; s >= 1; s >>= 1) {
        if (ch < s) {
            float4 a = smax[ch][lane4], bb = smax[ch + s][lane4];
            a.x = fmaxf(a.x, bb.x); a.y = fmaxf(a.y, bb.y);
            a.z = fmaxf(a.z, bb.z); a.w = fmaxf(a.w, bb.w);
            smax[ch][lane4] = a;
            float4 c = ssum[ch][lane4], d = ssum[ch + s][lane4];
            c.x += d.x; c.y += d.y; c.z += d.z; c.w += d.w;
            ssum[ch][lane4] = c;
        }
        __syncthreads();
    }
    if (ch == 0) {
        float4 m = smax[0][lane4];
        float4 s4 = ssum[0][lane4];
        float invk = 1.0f / (float)k;
        int f0 = lane4 * 4;
        float* hp = h + g * 256;
        hp[f0 + 0] += m.x; hp[f0 + 1] += m.y; hp[f0 + 2] += m.z; hp[f0 + 3] += m.w;
        hp[128 + f0 + 0] += s4.x * invk; hp[128 + f0 + 1] += s4.y * invk;
        hp[128 + f0 + 2] += s4.z * invk; hp[128 + f0 + 3] += s4.w * invk;
    }
}

// ---------------- remap edges + count next-layer deg/cnt ----------------
__global__ void remap_count_kernel(int* __restrict__ src, int* __restrict__ dst,
                                   const int* __restrict__ new_id,
                                   float* __restrict__ deg, int* __restrict__ cnt) {
    int e = blockIdx.x * blockDim.x + threadIdx.x;
    if (e < ETOT) {
        int s = src[e];
        if (s < 0) return;
        int d = dst[e];
        int s2 = new_id[s];
        int d2 = new_id[d];
        if (s2 >= 0 && d2 >= 0) {
            src[e] = s2;
            dst[e] = d2;
            atomicAdd(&deg[s2], 1.0f);
            atomicAdd(&cnt[d2], 1);
        } else {
            src[e] = -1;
            dst[e] = -1;
        }
    }
}

__global__ void head_kernel(const float* __restrict__ h,
                            const float* __restrict__ l1w, const float* __restrict__ l1b,
                            const float* __restrict__ l2w, const float* __restrict__ l2b,
                            const float* __restrict__ l3w, const float* __restrict__ l3b,
                            float* __restrict__ out) {
    __shared__ float hr[256];
    __shared__ float h1[128];
    __shared__ float h2[64];
    __shared__ float lz[2];
    int g = blockIdx.x, t = threadIdx.x;
    hr[t] = h[g * 256 + t];
    hr[t + 128] = h[g * 256 + 128 + t];
    __syncthreads();
    float acc = l1b[t];
    for (int d = 0; d < 256; d++) acc += hr[d] * l1w[t * 256 + d];
    h1[t] = fmaxf(acc, 0.f);
    __syncthreads();
    if (t < 64) {
        float a2 = l2b[t];
        for (int d = 0; d < 128; d++) a2 += h1[d] * l2w[t * 128 + d];
        h2[t] = fmaxf(a2, 0.f);
    }
    __syncthreads();
    if (t < 2) {
        float a3 = l3b[t];
        for (int d = 0; d < 64; d++) a3 += h2[d] * l3w[t * 64 + d];
        lz[t] = a3;
    }
    __syncthreads();
    if (t < 2) {
        float z0 = lz[0], z1 = lz[1];
        float m = fmaxf(z0, z1);
        float lse = m + logf(expf(z0 - m) + expf(z1 - m));
        out[g * 2 + t] = lz[t] - lse;
    }
}

extern "C" void kernel_launch(void* const* d_in, const int* in_sizes, int n_in,
                              void* d_out, int out_size, void* d_ws, size_t ws_size,
                              hipStream_t stream) {
    const float* x_in = (const float*)d_in[0];
    const int* edge_index = (const int*)d_in[1];
    const float *cw[5], *cb[5], *pw[5];
    for (int i = 0; i < 5; i++) {
        cw[i] = (const float*)d_in[3 + 3 * i];
        cb[i] = (const float*)d_in[4 + 3 * i];
        pw[i] = (const float*)d_in[5 + 3 * i];
    }
    const float* l1w = (const float*)d_in[18];
    const float* l1b = (const float*)d_in[19];
    const float* l2w = (const float*)d_in[20];
    const float* l2b = (const float*)d_in[21];
    const float* l3w = (const float*)d_in[22];
    const float* l3b = (const float*)d_in[23];
    float* out = (float*)d_out;

    char* w = (char*)d_ws;
    float* xA    = (float*)w; w += (size_t)65536 * DIM * 4;
    float* xB    = (float*)w; w += (size_t)65536 * DIM * 4;
    float* xL    = (float*)w; w += (size_t)65536 * DIM * 4;
    int*   src   = (int*)w;   w += (size_t)ETOT * 4;
    int*   dst   = (int*)w;   w += (size_t)ETOT * 4;
    int*   esrc_s= (int*)w;   w += (size_t)ETOT * 4;
    float* deg   = (float*)w; w += (size_t)65536 * 4;
    int*   cnt   = (int*)w;   w += (size_t)65536 * 4;
    int*   eoff  = (int*)w;   w += (size_t)65536 * 4;
    int*   cursor= (int*)w;   w += (size_t)65536 * 4;
    float* dinv  = (float*)w; w += (size_t)65536 * 4;
    float* score = (float*)w; w += (size_t)65536 * 4;
    float* skey  = (float*)w; w += (size_t)NB * 1024 * 4;
    int*   sidx  = (int*)w;   w += (size_t)NB * 1024 * 4;
    int*   newid = (int*)w;   w += (size_t)65536 * 4;
    float* hsum  = (float*)w; w += (size_t)NB * 256 * 4;
    float* invn  = (float*)w; w += 4;

    hipMemcpyAsync(src, edge_index, (size_t)ETOT * 4, hipMemcpyDeviceToDevice, stream);
    hipMemcpyAsync(dst, edge_index + ETOT, (size_t)ETOT * 4, hipMemcpyDeviceToDevice, stream);
    hipMemsetAsync(deg, 0, (size_t)65536 * 4, stream);
    hipMemsetAsync(cnt, 0, (size_t)65536 * 4, stream);
    hipMemsetAsync(hsum, 0, (size_t)NB * 256 * 4, stream);
    init_count_kernel<<<ETOT / 256, 256, 0, stream>>>(src, dst, deg, cnt);

    const float* xin = x_in;
    for (int i = 0; i < 5; i++) {
        int n = NS_H[i], k = NS_H[i + 1];
        int N = NB * n;

        linear_kernel<<<(N + 127) / 128, 128, 0, stream>>>(xin, cw[i], cb[i], xL, N);
        scan_graph_kernel<<<NB, 1024, 0, stream>>>(cnt, deg, dinv, eoff, cursor, n, pw[i], invn);
        scatter_kernel<<<ETOT / 256, 256, 0, stream>>>(src, dst, cursor, esrc_s);

        int gpb = (n + 7) / 8;
        fused_agg_kernel<<<NB * gpb, 256, 0, stream>>>(xL, esrc_s, eoff, cnt, dinv, pw[i],
                                                       invn, xA, score, n);

        topk_sort_kernel<<<NB, 512, 0, stream>>>(score, n, k, skey, sidx, newid, deg, cnt);
        gather_readout_kernel<<<NB, 1024, 0, stream>>>(xA, skey, sidx, xB, hsum, n, k);
        if (i < 4)
            remap_count_kernel<<<ETOT / 256, 256, 0, stream>>>(src, dst, newid, deg, cnt);

        xin = xB;
    }

    head_kernel<<<NB, 128, 0, stream>>>(hsum, l1w, l1b, l2w, l2b, l3w, l3b, out);
}

// Round 6
// 1036.324 us; speedup vs baseline: 5.8722x; 1.0325x over previous
//
#include <hip/hip_runtime.h>
#include <math.h>

#define NB 64
#define DIM 128
#define ETOT 1048576
#define EPG 16384   // edges-per-graph region (ETOT / NB)
#define WRS 192     // LDS row stride (floats) for W tile (16 frags * 12)
#define XRS 96      // LDS row stride for x tile (8 frags * 12)

static const int NS_H[6] = {1024, 820, 656, 525, 420, 336};

// ---------------- initial degree/count via per-graph LDS histogram ----------------
__global__ __launch_bounds__(256) void init_count_kernel(const int* __restrict__ src,
                                  const int* __restrict__ dst,
                                  float* __restrict__ deg, int* __restrict__ cnt) {
    __shared__ int hs[1024], hc[1024];
    int g = blockIdx.x, t = threadIdx.x;
    for (int i = t; i < 1024; i += 256) { hs[i] = 0; hc[i] = 0; }
    __syncthreads();
    int b0 = g * EPG;
    for (int e = b0 + t; e < b0 + EPG; e += 256) {
        atomicAdd(&hs[src[e] & 1023], 1);
        atomicAdd(&hc[dst[e] & 1023], 1);
    }
    __syncthreads();
    for (int i = t; i < 1024; i += 256) {
        deg[g * 1024 + i] = (float)hs[i];
        cnt[g * 1024 + i] = hc[i];
    }
}

// ---------------- linear: y = x @ W.T + b ----------------
// 256 threads, tile 64 nodes x 128 feats, K sliced 4x32. Grid = N/64 (exact).
// Fragment swizzle: row r -> slot (r>>3)*12 + (r&7): float4-aligned frag starts,
// conflict-free (<=2-way) LDS reads and writes. 36.9 KB LDS -> 4 blocks/CU.
__global__ __launch_bounds__(256) void linear_kernel(const float* __restrict__ x,
                              const float* __restrict__ W, const float* __restrict__ b,
                              float* __restrict__ y, int N) {
    __shared__ float Wt[32 * WRS];
    __shared__ float xT[32 * XRS];
    int tid = threadIdx.x;
    int base = blockIdx.x * 64;
    int nf = tid & 15;          // node fragment: 4 nodes
    int u  = tid >> 4;          // feat fragment: 8 feats
    float acc[4][8];
    {
        float bv[8];
#pragma unroll
        for (int f = 0; f < 8; f++) bv[f] = b[u * 8 + f];
#pragma unroll
        for (int i = 0; i < 4; i++)
#pragma unroll
            for (int f = 0; f < 8; f++) acc[i][f] = bv[f];
    }

    for (int kb = 0; kb < 4; kb++) {
        __syncthreads();
        // stage W slice: 128 rows x 32 d; dq wave-uniform -> 2-way LDS writes max
#pragma unroll
        for (int q = 0; q < 4; q++) {
            int i = q * 256 + tid;
            int dq = i >> 7;             // 0..7, uniform within a wave
            int r = i & 127;
            int s = (r >> 3) * 12 + (r & 7);
            float4 wv = *(const float4*)(W + r * 128 + kb * 32 + dq * 4);
            Wt[(dq * 4 + 0) * WRS + s] = wv.x;
            Wt[(dq * 4 + 1) * WRS + s] = wv.y;
            Wt[(dq * 4 + 2) * WRS + s] = wv.z;
            Wt[(dq * 4 + 3) * WRS + s] = wv.w;
        }
        // stage x slice: 64 rows x 32 d
#pragma unroll
        for (int q = 0; q < 2; q++) {
            int i = q * 256 + tid;
            int dq = i >> 6;             // 0..7, uniform within a wave
            int r = i & 63;
            int s = (r >> 3) * 12 + (r & 7);
            float4 xv = *(const float4*)(x + (size_t)(base + r) * DIM + kb * 32 + dq * 4);
            xT[(dq * 4 + 0) * XRS + s] = xv.x;
            xT[(dq * 4 + 1) * XRS + s] = xv.y;
            xT[(dq * 4 + 2) * XRS + s] = xv.z;
            xT[(dq * 4 + 3) * XRS + s] = xv.w;
        }
        __syncthreads();
#pragma unroll 4
        for (int d = 0; d < 32; d++) {
            float4 xv = *(const float4*)&xT[d * XRS + (nf >> 1) * 12 + (nf & 1) * 4];
            float4 wa = *(const float4*)&Wt[d * WRS + u * 12];
            float4 wb = *(const float4*)&Wt[d * WRS + u * 12 + 4];
            float xs[4] = {xv.x, xv.y, xv.z, xv.w};
            float ws[8] = {wa.x, wa.y, wa.z, wa.w, wb.x, wb.y, wb.z, wb.w};
#pragma unroll
            for (int i = 0; i < 4; i++)
#pragma unroll
                for (int f = 0; f < 8; f++)
                    acc[i][f] += xs[i] * ws[f];
        }
    }
#pragma unroll
    for (int i = 0; i < 4; i++) {
        int nd = base + nf * 4 + i;
        float* yp = y + (size_t)nd * DIM + u * 8;
        *(float4*)(yp + 0) = make_float4(acc[i][0], acc[i][1], acc[i][2], acc[i][3]);
        *(float4*)(yp + 4) = make_float4(acc[i][4], acc[i][5], acc[i][6], acc[i][7]);
    }
}

// ---------------- per-graph scan + dinv precompute + (block0) pw invnorm ----------------
__global__ __launch_bounds__(1024) void scan_graph_kernel(const int* __restrict__ cnt,
                            const float* __restrict__ deg, float* __restrict__ dinv,
                            int* __restrict__ eoff, int n,
                            const float* __restrict__ pw, float* __restrict__ invn) {
    __shared__ int sh[1024];
    __shared__ float shf[128];
    int g = blockIdx.x, t = threadIdx.x;
    int v = (t < n) ? cnt[g * n + t] : 0;
    sh[t] = v;
    __syncthreads();
    for (int off = 1; off < 1024; off <<= 1) {
        int u = (t >= off) ? sh[t - off] : 0;
        __syncthreads();
        sh[t] += u;
        __syncthreads();
    }
    if (t < n) {
        eoff[g * n + t] = g * EPG + sh[t] - v;
        dinv[g * n + t] = rsqrtf(deg[g * n + t] + 1.0f);
    }
    if (g == 0) {
        if (t < 128) shf[t] = pw[t] * pw[t];
        __syncthreads();
        for (int s = 64; s > 0; s >>= 1) {
            if (t < s) shf[t] += shf[t + s];
            __syncthreads();
        }
        if (t == 0) invn[0] = rsqrtf(shf[0]);
    }
}

// ---------------- scatter valid edges into CSR by dst (per-graph LDS cursor) ----------------
__global__ __launch_bounds__(256) void scatter_kernel(const int* __restrict__ src,
                               const int* __restrict__ dst, const int* __restrict__ eoff,
                               int* __restrict__ esrc_s, int n) {
    __shared__ int cur[1024];
    int g = blockIdx.x, t = threadIdx.x;
    for (int i = t; i < n; i += 256) cur[i] = eoff[g * n + i];
    __syncthreads();
    int b0 = g * EPG;
    for (int e = b0 + t; e < b0 + EPG; e += 256) {
        int s = src[e];
        if (s >= 0) {
            int pos = atomicAdd(&cur[dst[e] - g * n], 1);
            esrc_s[pos] = s;
        }
    }
}

// ---------------- fused aggregate + self + relu + score (XCD-swizzled) ----------------
__global__ void fused_agg_kernel(const float* __restrict__ xL, const int* __restrict__ esrc,
                                 const int* __restrict__ eoff, const int* __restrict__ cnt,
                                 const float* __restrict__ dinv,
                                 const float* __restrict__ pw, const float* __restrict__ invn,
                                 float* __restrict__ xA, float* __restrict__ score, int n) {
    int t = threadIdx.x;
    int g = blockIdx.x % NB;
    int chunk = blockIdx.x / NB;
    int ln = chunk * 8 + (t >> 5);
    if (ln >= n) return;
    int node = g * n + ln;
    int lane = t & 31;
    float dsn = dinv[node];
    const float4* selfp = (const float4*)(xL + (size_t)node * DIM);
    float4 sv = selfp[lane];
    float inv_dn = dsn * dsn;
    float4 acc = make_float4(sv.x * inv_dn, sv.y * inv_dn, sv.z * inv_dn, sv.w * inv_dn);
    int s0 = eoff[node], s1 = s0 + cnt[node];
    for (int j = s0; j < s1; j++) {
        int s = esrc[j];
        float norm = dsn * dinv[s];
        const float4* xp = (const float4*)(xL + (size_t)s * DIM);
        float4 xv = xp[lane];
        acc.x += norm * xv.x;
        acc.y += norm * xv.y;
        acc.z += norm * xv.z;
        acc.w += norm * xv.w;
    }
    acc.x = fmaxf(acc.x, 0.f);
    acc.y = fmaxf(acc.y, 0.f);
    acc.z = fmaxf(acc.z, 0.f);
    acc.w = fmaxf(acc.w, 0.f);
    ((float4*)(xA + (size_t)node * DIM))[lane] = acc;
    const float4* pwp = (const float4*)pw;
    float4 pv = pwp[lane];
    float dot = acc.x * pv.x + acc.y * pv.y + acc.z * pv.z + acc.w * pv.w;
    for (int off = 16; off >= 1; off >>= 1) dot += __shfl_xor(dot, off, 32);
    if (lane == 0) score[node] = tanhf(dot * invn[0]);
}

// ---------------- bitonic sort + newid build ----------------
__global__ __launch_bounds__(512) void topk_sort_kernel(const float* __restrict__ sc, int n,
                                 int k, float* __restrict__ skey_out, int* __restrict__ sidx_out,
                                 int* __restrict__ new_id) {
    __shared__ float key[1024];
    __shared__ int idx[1024];
    int g = blockIdx.x;
    for (int i = threadIdx.x; i < 1024; i += blockDim.x) {
        if (i < n) { key[i] = sc[g * n + i]; idx[i] = i; }
        else       { key[i] = -2.0f;         idx[i] = i; }
    }
    __syncthreads();
    for (unsigned ksz = 2; ksz <= 1024; ksz <<= 1) {
        for (unsigned j = ksz >> 1; j > 0; j >>= 1) {
            for (unsigned i = threadIdx.x; i < 1024; i += blockDim.x) {
                unsigned ixj = i ^ j;
                if (ixj > i) {
                    float ka = key[i], kb = key[ixj];
                    int ia = idx[i], ib = idx[ixj];
                    bool aLess = (ka > kb) || (ka == kb && ia < ib);
                    bool up = ((i & ksz) == 0);
                    bool sw = up ? !aLess : aLess;
                    if (sw) { key[i] = kb; key[ixj] = ka; idx[i] = ib; idx[ixj] = ia; }
                }
            }
            __syncthreads();
        }
    }
    for (int i = threadIdx.x; i < 1024; i += blockDim.x) {
        skey_out[g * 1024 + i] = key[i];
        sidx_out[g * 1024 + i] = idx[i];
        if (i < n) new_id[g * n + idx[i]] = (i < k) ? (g * k + i) : -1;
    }
}

// ---------------- fused gather (xn = x[perm]*s) + readout max/mean ----------------
__global__ __launch_bounds__(1024) void gather_readout_kernel(const float* __restrict__ xA,
                              const float* __restrict__ skey, const int* __restrict__ sidx,
                              float* __restrict__ xn, float* __restrict__ h, int n, int k) {
    __shared__ float4 smax[32][33];
    __shared__ float4 ssum[32][33];
    int g = blockIdx.x;
    int t = threadIdx.x;
    int lane4 = t & 31;
    int ch = t >> 5;
    float4 mx = make_float4(-INFINITY, -INFINITY, -INFINITY, -INFINITY);
    float4 sm = make_float4(0.f, 0.f, 0.f, 0.f);
    for (int j = ch; j < k; j += 32) {
        int row = sidx[g * 1024 + j];
        float sval = skey[g * 1024 + j];
        float4 v = ((const float4*)(xA + ((size_t)g * n + row) * DIM))[lane4];
        v.x *= sval; v.y *= sval; v.z *= sval; v.w *= sval;
        ((float4*)(xn + ((size_t)g * k + j) * DIM))[lane4] = v;
        mx.x = fmaxf(mx.x, v.x); mx.y = fmaxf(mx.y, v.y);
        mx.z = fmaxf(mx.z, v.z); mx.w = fmaxf(mx.w, v.w);
        sm.x += v.x; sm.y += v.y; sm.z += v.z; sm.w += v.w;
    }
    smax[ch][lane4] = mx;
    ssum[ch][lane4] = sm;
    __syncthreads();
    for (int s = 16; s >= 1; s >>= 1) {
        if (ch < s) {
            float4 a = smax[ch][lane4], bb = smax[ch + s][lane4];
            a.x = fmaxf(a.x, bb.x); a.y = fmaxf(a.y, bb.y);
            a.z = fmaxf(a.z, bb.z); a.w = fmaxf(a.w, bb.w);
            smax[ch][lane4] = a;
            float4 c = ssum[ch][lane4], d = ssum[ch + s][lane4];
            c.x += d.x; c.y += d.y; c.z += d.z; c.w += d.w;
            ssum[ch][lane4] = c;
        }
        __syncthreads();
    }
    if (ch == 0) {
        float4 m = smax[0][lane4];
        float4 s4 = ssum[0][lane4];
        float invk = 1.0f / (float)k;
        int f0 = lane4 * 4;
        float* hp = h + g * 256;
        hp[f0 + 0] += m.x; hp[f0 + 1] += m.y; hp[f0 + 2] += m.z; hp[f0 + 3] += m.w;
        hp[128 + f0 + 0] += s4.x * invk; hp[128 + f0 + 1] += s4.y * invk;
        hp[128 + f0 + 2] += s4.z * invk; hp[128 + f0 + 3] += s4.w * invk;
    }
}

// ---------------- remap edges + next-layer deg/cnt via per-graph LDS histogram ----------------
__global__ __launch_bounds__(256) void remap_count_kernel(int* __restrict__ src,
                                   int* __restrict__ dst, const int* __restrict__ new_id,
                                   float* __restrict__ deg, int* __restrict__ cnt, int k) {
    __shared__ int hs[1024], hc[1024];
    int g = blockIdx.x, t = threadIdx.x;
    for (int i = t; i < k; i += 256) { hs[i] = 0; hc[i] = 0; }
    __syncthreads();
    int b0 = g * EPG;
    for (int e = b0 + t; e < b0 + EPG; e += 256) {
        int s = src[e];
        if (s < 0) continue;
        int s2 = new_id[s];
        int d2 = new_id[dst[e]];
        if (s2 >= 0 && d2 >= 0) {
            src[e] = s2;
            dst[e] = d2;
            atomicAdd(&hs[s2 - g * k], 1);
            atomicAdd(&hc[d2 - g * k], 1);
        } else {
            src[e] = -1;
            dst[e] = -1;
        }
    }
    __syncthreads();
    for (int i = t; i < k; i += 256) {
        deg[g * k + i] = (float)hs[i];
        cnt[g * k + i] = hc[i];
    }
}

__global__ void head_kernel(const float* __restrict__ h,
                            const float* __restrict__ l1w, const float* __restrict__ l1b,
                            const float* __restrict__ l2w, const float* __restrict__ l2b,
                            const float* __restrict__ l3w, const float* __restrict__ l3b,
                            float* __restrict__ out) {
    __shared__ float hr[256];
    __shared__ float h1[128];
    __shared__ float h2[64];
    __shared__ float lz[2];
    int g = blockIdx.x, t = threadIdx.x;
    hr[t] = h[g * 256 + t];
    hr[t + 128] = h[g * 256 + 128 + t];
    __syncthreads();
    float acc = l1b[t];
    for (int d = 0; d < 256; d++) acc += hr[d] * l1w[t * 256 + d];
    h1[t] = fmaxf(acc, 0.f);
    __syncthreads();
    if (t < 64) {
        float a2 = l2b[t];
        for (int d = 0; d < 128; d++) a2 += h1[d] * l2w[t * 128 + d];
        h2[t] = fmaxf(a2, 0.f);
    }
    __syncthreads();
    if (t < 2) {
        float a3 = l3b[t];
        for (int d = 0; d < 64; d++) a3 += h2[d] * l3w[t * 64 + d];
        lz[t] = a3;
    }
    __syncthreads();
    if (t < 2) {
        float z0 = lz[0], z1 = lz[1];
        float m = fmaxf(z0, z1);
        float lse = m + logf(expf(z0 - m) + expf(z1 - m));
        out[g * 2 + t] = lz[t] - lse;
    }
}

extern "C" void kernel_launch(void* const* d_in, const int* in_sizes, int n_in,
                              void* d_out, int out_size, void* d_ws, size_t ws_size,
                              hipStream_t stream) {
    const float* x_in = (const float*)d_in[0];
    const int* edge_index = (const int*)d_in[1];
    const float *cw[5], *cb[5], *pw[5];
    for (int i = 0; i < 5; i++) {
        cw[i] = (const float*)d_in[3 + 3 * i];
        cb[i] = (const float*)d_in[4 + 3 * i];
        pw[i] = (const float*)d_in[5 + 3 * i];
    }
    const float* l1w = (const float*)d_in[18];
    const float* l1b = (const float*)d_in[19];
    const float* l2w = (const float*)d_in[20];
    const float* l2b = (const float*)d_in[21];
    const float* l3w = (const float*)d_in[22];
    const float* l3b = (const float*)d_in[23];
    float* out = (float*)d_out;

    char* w = (char*)d_ws;
    float* xA    = (float*)w; w += (size_t)65536 * DIM * 4;
    float* xB    = (float*)w; w += (size_t)65536 * DIM * 4;
    float* xL    = (float*)w; w += (size_t)65536 * DIM * 4;
    int*   src   = (int*)w;   w += (size_t)ETOT * 4;
    int*   dst   = (int*)w;   w += (size_t)ETOT * 4;
    int*   esrc_s= (int*)w;   w += (size_t)ETOT * 4;
    float* deg   = (float*)w; w += (size_t)65536 * 4;
    int*   cnt   = (int*)w;   w += (size_t)65536 * 4;
    int*   eoff  = (int*)w;   w += (size_t)65536 * 4;
    float* dinv  = (float*)w; w += (size_t)65536 * 4;
    float* score = (float*)w; w += (size_t)65536 * 4;
    float* skey  = (float*)w; w += (size_t)NB * 1024 * 4;
    int*   sidx  = (int*)w;   w += (size_t)NB * 1024 * 4;
    int*   newid = (int*)w;   w += (size_t)65536 * 4;
    float* hsum  = (float*)w; w += (size_t)NB * 256 * 4;
    float* invn  = (float*)w; w += 4;

    hipMemcpyAsync(src, edge_index, (size_t)ETOT * 4, hipMemcpyDeviceToDevice, stream);
    hipMemcpyAsync(dst, edge_index + ETOT, (size_t)ETOT * 4, hipMemcpyDeviceToDevice, stream);
    hipMemsetAsync(hsum, 0, (size_t)NB * 256 * 4, stream);
    init_count_kernel<<<NB, 256, 0, stream>>>(src, dst, deg, cnt);

    const float* xin = x_in;
    for (int i = 0; i < 5; i++) {
        int n = NS_H[i], k = NS_H[i + 1];
        int N = NB * n;

        linear_kernel<<<N / 64, 256, 0, stream>>>(xin, cw[i], cb[i], xL, N);
        scan_graph_kernel<<<NB, 1024, 0, stream>>>(cnt, deg, dinv, eoff, n, pw[i], invn);
        scatter_kernel<<<NB, 256, 0, stream>>>(src, dst, eoff, esrc_s, n);

        int gpb = (n + 7) / 8;
        fused_agg_kernel<<<NB * gpb, 256, 0, stream>>>(xL, esrc_s, eoff, cnt, dinv, pw[i],
                                                       invn, xA, score, n);

        topk_sort_kernel<<<NB, 512, 0, stream>>>(score, n, k, skey, sidx, newid);
        gather_readout_kernel<<<NB, 1024, 0, stream>>>(xA, skey, sidx, xB, hsum, n, k);
        if (i < 4)
            remap_count_kernel<<<NB, 256, 0, stream>>>(src, dst, newid, deg, cnt, k);

        xin = xB;
    }

    head_kernel<<<NB, 128, 0, stream>>>(hsum, l1w, l1b, l2w, l2b, l3w, l3b, out);
}

// Round 7
// 672.900 us; speedup vs baseline: 9.0437x; 1.5401x over previous
//
#include <hip/hip_runtime.h>
#include <math.h>

#define NB 64
#define DIM 128
#define ETOT 1048576
#define EPG 16384   // edges-per-graph region (ETOT / NB)
#define WRS 192     // LDS row stride (floats) for W tile
#define XRS 96      // LDS row stride for x tile

static const int NS_H[6] = {1024, 820, 656, 525, 420, 336};

// ---------------- init: copy edges, histogram deg/cnt, zero hsum ----------------
__global__ __launch_bounds__(256) void init_kernel(const int* __restrict__ ei,
                                  int* __restrict__ src, int* __restrict__ dst,
                                  float* __restrict__ deg, int* __restrict__ cnt,
                                  float* __restrict__ hsum) {
    __shared__ int hs[1024], hc[1024];
    int g = blockIdx.x, t = threadIdx.x;
    for (int i = t; i < 1024; i += 256) { hs[i] = 0; hc[i] = 0; }
    __syncthreads();
    int b0 = g * EPG;
    for (int e = b0 + t; e < b0 + EPG; e += 256) {
        int s = ei[e];
        int d = ei[ETOT + e];
        src[e] = s;
        dst[e] = d;
        atomicAdd(&hs[s & 1023], 1);
        atomicAdd(&hc[d & 1023], 1);
    }
    __syncthreads();
    for (int i = t; i < 1024; i += 256) {
        deg[g * 1024 + i] = (float)hs[i];
        cnt[g * 1024 + i] = hc[i];
    }
    hsum[g * 256 + t] = 0.f;
}

// ---------------- linear: y = x @ W.T + b (64n x 128f tile, conflict-free swizzle) ----------------
__global__ __launch_bounds__(256) void linear_kernel(const float* __restrict__ x,
                              const float* __restrict__ W, const float* __restrict__ b,
                              float* __restrict__ y, int N) {
    __shared__ float Wt[32 * WRS];
    __shared__ float xT[32 * XRS];
    int tid = threadIdx.x;
    int base = blockIdx.x * 64;
    int nf = tid & 15;
    int u  = tid >> 4;
    float acc[4][8];
    {
        float bv[8];
#pragma unroll
        for (int f = 0; f < 8; f++) bv[f] = b[u * 8 + f];
#pragma unroll
        for (int i = 0; i < 4; i++)
#pragma unroll
            for (int f = 0; f < 8; f++) acc[i][f] = bv[f];
    }
    for (int kb = 0; kb < 4; kb++) {
        __syncthreads();
#pragma unroll
        for (int q = 0; q < 4; q++) {
            int i = q * 256 + tid;
            int dq = i >> 7;
            int r = i & 127;
            int s = (r >> 3) * 12 + (r & 7);
            float4 wv = *(const float4*)(W + r * 128 + kb * 32 + dq * 4);
            Wt[(dq * 4 + 0) * WRS + s] = wv.x;
            Wt[(dq * 4 + 1) * WRS + s] = wv.y;
            Wt[(dq * 4 + 2) * WRS + s] = wv.z;
            Wt[(dq * 4 + 3) * WRS + s] = wv.w;
        }
#pragma unroll
        for (int q = 0; q < 2; q++) {
            int i = q * 256 + tid;
            int dq = i >> 6;
            int r = i & 63;
            int s = (r >> 3) * 12 + (r & 7);
            float4 xv = *(const float4*)(x + (size_t)(base + r) * DIM + kb * 32 + dq * 4);
            xT[(dq * 4 + 0) * XRS + s] = xv.x;
            xT[(dq * 4 + 1) * XRS + s] = xv.y;
            xT[(dq * 4 + 2) * XRS + s] = xv.z;
            xT[(dq * 4 + 3) * XRS + s] = xv.w;
        }
        __syncthreads();
#pragma unroll 4
        for (int d = 0; d < 32; d++) {
            float4 xv = *(const float4*)&xT[d * XRS + (nf >> 1) * 12 + (nf & 1) * 4];
            float4 wa = *(const float4*)&Wt[d * WRS + u * 12];
            float4 wb = *(const float4*)&Wt[d * WRS + u * 12 + 4];
            float xs[4] = {xv.x, xv.y, xv.z, xv.w};
            float ws[8] = {wa.x, wa.y, wa.z, wa.w, wb.x, wb.y, wb.z, wb.w};
#pragma unroll
            for (int i = 0; i < 4; i++)
#pragma unroll
                for (int f = 0; f < 8; f++)
                    acc[i][f] += xs[i] * ws[f];
        }
    }
#pragma unroll
    for (int i = 0; i < 4; i++) {
        int nd = base + nf * 4 + i;
        float* yp = y + (size_t)nd * DIM + u * 8;
        *(float4*)(yp + 0) = make_float4(acc[i][0], acc[i][1], acc[i][2], acc[i][3]);
        *(float4*)(yp + 4) = make_float4(acc[i][4], acc[i][5], acc[i][6], acc[i][7]);
    }
}

// ---------------- scan + scatter fused: CSR build with packed {src, norm} ----------------
__global__ __launch_bounds__(1024) void scan_scatter_kernel(const int* __restrict__ cnt,
                            const float* __restrict__ deg, float* __restrict__ dinv,
                            int* __restrict__ eoff, const int* __restrict__ src,
                            const int* __restrict__ dst, int2* __restrict__ epack, int n,
                            const float* __restrict__ pw, float* __restrict__ invn) {
    __shared__ int sh[1024];
    __shared__ int cur[1024];
    __shared__ float dv[1024];
    __shared__ float shf[128];
    int g = blockIdx.x, t = threadIdx.x;
    int v = (t < n) ? cnt[g * n + t] : 0;
    sh[t] = v;
    float dl = (t < n) ? rsqrtf(deg[g * n + t] + 1.0f) : 0.f;
    dv[t] = dl;
    __syncthreads();
    for (int off = 1; off < 1024; off <<= 1) {
        int u = (t >= off) ? sh[t - off] : 0;
        __syncthreads();
        sh[t] += u;
        __syncthreads();
    }
    if (t < n) {
        int pos = g * EPG + sh[t] - v;
        eoff[g * n + t] = pos;
        cur[t] = pos;
        dinv[g * n + t] = dl;
    }
    if (g == 0) {
        if (t < 128) shf[t] = pw[t] * pw[t];
        __syncthreads();
        for (int s = 64; s > 0; s >>= 1) {
            if (t < s) shf[t] += shf[t + s];
            __syncthreads();
        }
        if (t == 0) invn[0] = rsqrtf(shf[0]);
    }
    __syncthreads();
    int b0 = g * EPG, gn = g * n;
    for (int e = b0 + t; e < b0 + EPG; e += 1024) {
        int s = src[e];
        if (s >= 0) {
            int dloc = dst[e] - gn;
            int pos = atomicAdd(&cur[dloc], 1);
            epack[pos] = make_int2(s, __float_as_int(dv[s - gn] * dv[dloc]));
        }
    }
}

// ---------------- fused aggregate + self + relu + score (packed edges, unroll 2) ----------------
__global__ void fused_agg_kernel(const float* __restrict__ xL, const int2* __restrict__ epack,
                                 const int* __restrict__ eoff, const int* __restrict__ cnt,
                                 const float* __restrict__ dinv,
                                 const float* __restrict__ pw, const float* __restrict__ invn,
                                 float* __restrict__ xA, float* __restrict__ score, int n) {
    int t = threadIdx.x;
    int g = blockIdx.x % NB;
    int chunk = blockIdx.x / NB;
    int ln = chunk * 8 + (t >> 5);
    if (ln >= n) return;
    int node = g * n + ln;
    int lane = t & 31;
    float dsn = dinv[node];
    float4 sv = ((const float4*)(xL + (size_t)node * DIM))[lane];
    float w0 = dsn * dsn;
    float4 acc0 = make_float4(sv.x * w0, sv.y * w0, sv.z * w0, sv.w * w0);
    float4 acc1 = make_float4(0.f, 0.f, 0.f, 0.f);
    int s0 = eoff[node], s1 = s0 + cnt[node];
    int j = s0;
    for (; j + 1 < s1; j += 2) {
        int2 e0 = epack[j];
        int2 e1 = epack[j + 1];
        float n0 = __int_as_float(e0.y);
        float n1 = __int_as_float(e1.y);
        float4 x0 = ((const float4*)(xL + (size_t)e0.x * DIM))[lane];
        float4 x1 = ((const float4*)(xL + (size_t)e1.x * DIM))[lane];
        acc0.x += n0 * x0.x; acc0.y += n0 * x0.y; acc0.z += n0 * x0.z; acc0.w += n0 * x0.w;
        acc1.x += n1 * x1.x; acc1.y += n1 * x1.y; acc1.z += n1 * x1.z; acc1.w += n1 * x1.w;
    }
    if (j < s1) {
        int2 e0 = epack[j];
        float n0 = __int_as_float(e0.y);
        float4 x0 = ((const float4*)(xL + (size_t)e0.x * DIM))[lane];
        acc0.x += n0 * x0.x; acc0.y += n0 * x0.y; acc0.z += n0 * x0.z; acc0.w += n0 * x0.w;
    }
    float4 acc = make_float4(fmaxf(acc0.x + acc1.x, 0.f), fmaxf(acc0.y + acc1.y, 0.f),
                             fmaxf(acc0.z + acc1.z, 0.f), fmaxf(acc0.w + acc1.w, 0.f));
    ((float4*)(xA + (size_t)node * DIM))[lane] = acc;
    float4 pv = ((const float4*)pw)[lane];
    float dot = acc.x * pv.x + acc.y * pv.y + acc.z * pv.z + acc.w * pv.w;
    for (int off = 16; off >= 1; off >>= 1) dot += __shfl_xor(dot, off, 32);
    if (lane == 0) score[node] = tanhf(dot * invn[0]);
}

// ---------------- pool: sort + newid + gather + readout + remap + count, all per-graph ----------------
__global__ __launch_bounds__(1024) void pool_kernel(const float* __restrict__ score,
                              const float* __restrict__ xA, float* __restrict__ xn,
                              float* __restrict__ h, int* __restrict__ src,
                              int* __restrict__ dst, float* __restrict__ deg,
                              int* __restrict__ cnt, int n, int k) {
    __shared__ float key[1024];
    __shared__ int idx[1024];
    __shared__ int nid[1024];
    __shared__ float4 smax[32][33];
    __shared__ float4 ssum[32][33];
    __shared__ int hs[1024], hc[1024];
    int g = blockIdx.x, t = threadIdx.x;
    // ---- load scores (sentinel -2 beyond n; tanh in (-1,1)) ----
    if (t < n) { key[t] = score[g * n + t]; idx[t] = t; }
    else       { key[t] = -2.0f;            idx[t] = t; }
    __syncthreads();
    // ---- bitonic sort: desc score, ties -> lower idx (matches jax.lax.top_k) ----
    for (unsigned ksz = 2; ksz <= 1024; ksz <<= 1) {
        for (unsigned jj = ksz >> 1; jj > 0; jj >>= 1) {
            unsigned i = t, ixj = i ^ jj;
            if (ixj > i) {
                float ka = key[i], kb = key[ixj];
                int ia = idx[i], ib = idx[ixj];
                bool aLess = (ka > kb) || (ka == kb && ia < ib);
                bool up = ((i & ksz) == 0);
                if (up ? !aLess : aLess) {
                    key[i] = kb; key[ixj] = ka; idx[i] = ib; idx[ixj] = ia;
                }
            }
            __syncthreads();
        }
    }
    // ---- local new ids ----
    nid[idx[t]] = (t < (unsigned)k) ? t : -1;
    __syncthreads();
    // ---- gather xn = xA[perm]*s + readout max/mean ----
    int lane4 = t & 31;
    int ch = t >> 5;
    float4 mx = make_float4(-INFINITY, -INFINITY, -INFINITY, -INFINITY);
    float4 sm = make_float4(0.f, 0.f, 0.f, 0.f);
    for (int j = ch; j < k; j += 32) {
        int row = idx[j];
        float sval = key[j];
        float4 v = ((const float4*)(xA + ((size_t)g * n + row) * DIM))[lane4];
        v.x *= sval; v.y *= sval; v.z *= sval; v.w *= sval;
        ((float4*)(xn + ((size_t)g * k + j) * DIM))[lane4] = v;
        mx.x = fmaxf(mx.x, v.x); mx.y = fmaxf(mx.y, v.y);
        mx.z = fmaxf(mx.z, v.z); mx.w = fmaxf(mx.w, v.w);
        sm.x += v.x; sm.y += v.y; sm.z += v.z; sm.w += v.w;
    }
    smax[ch][lane4] = mx;
    ssum[ch][lane4] = sm;
    __syncthreads();
    for (int s = 16; s >= 1; s >>= 1) {
        if (ch < s) {
            float4 a = smax[ch][lane4], bb = smax[ch + s][lane4];
            a.x = fmaxf(a.x, bb.x); a.y = fmaxf(a.y, bb.y);
            a.z = fmaxf(a.z, bb.z); a.w = fmaxf(a.w, bb.w);
            smax[ch][lane4] = a;
            float4 c = ssum[ch][lane4], d = ssum[ch + s][lane4];
            c.x += d.x; c.y += d.y; c.z += d.z; c.w += d.w;
            ssum[ch][lane4] = c;
        }
        __syncthreads();
    }
    if (ch == 0) {
        float4 m = smax[0][lane4];
        float4 s4 = ssum[0][lane4];
        float invk = 1.0f / (float)k;
        int f0 = lane4 * 4;
        float* hp = h + g * 256;
        hp[f0 + 0] += m.x; hp[f0 + 1] += m.y; hp[f0 + 2] += m.z; hp[f0 + 3] += m.w;
        hp[128 + f0 + 0] += s4.x * invk; hp[128 + f0 + 1] += s4.y * invk;
        hp[128 + f0 + 2] += s4.z * invk; hp[128 + f0 + 3] += s4.w * invk;
    }
    // ---- remap edges + next-layer deg/cnt histogram ----
    if (t < (unsigned)k) { hs[t] = 0; hc[t] = 0; }
    __syncthreads();
    int b0 = g * EPG, gn = g * n, gk = g * k;
    for (int e = b0 + t; e < b0 + EPG; e += 1024) {
        int s = src[e];
        if (s < 0) continue;
        int s2 = nid[s - gn];
        int d2 = nid[dst[e] - gn];
        if (s2 >= 0 && d2 >= 0) {
            src[e] = gk + s2;
            dst[e] = gk + d2;
            atomicAdd(&hs[s2], 1);
            atomicAdd(&hc[d2], 1);
        } else {
            src[e] = -1;
            dst[e] = -1;
        }
    }
    __syncthreads();
    if (t < (unsigned)k) {
        deg[gk + t] = (float)hs[t];
        cnt[gk + t] = hc[t];
    }
}

// ---------------- MLP head + log_softmax ----------------
__global__ void head_kernel(const float* __restrict__ h,
                            const float* __restrict__ l1w, const float* __restrict__ l1b,
                            const float* __restrict__ l2w, const float* __restrict__ l2b,
                            const float* __restrict__ l3w, const float* __restrict__ l3b,
                            float* __restrict__ out) {
    __shared__ float hr[256];
    __shared__ float h1[128];
    __shared__ float h2[64];
    __shared__ float lz[2];
    int g = blockIdx.x, t = threadIdx.x;
    hr[t] = h[g * 256 + t];
    hr[t + 128] = h[g * 256 + 128 + t];
    __syncthreads();
    float acc = l1b[t];
    for (int d = 0; d < 256; d++) acc += hr[d] * l1w[t * 256 + d];
    h1[t] = fmaxf(acc, 0.f);
    __syncthreads();
    if (t < 64) {
        float a2 = l2b[t];
        for (int d = 0; d < 128; d++) a2 += h1[d] * l2w[t * 128 + d];
        h2[t] = fmaxf(a2, 0.f);
    }
    __syncthreads();
    if (t < 2) {
        float a3 = l3b[t];
        for (int d = 0; d < 64; d++) a3 += h2[d] * l3w[t * 64 + d];
        lz[t] = a3;
    }
    __syncthreads();
    if (t < 2) {
        float z0 = lz[0], z1 = lz[1];
        float m = fmaxf(z0, z1);
        float lse = m + logf(expf(z0 - m) + expf(z1 - m));
        out[g * 2 + t] = lz[t] - lse;
    }
}

extern "C" void kernel_launch(void* const* d_in, const int* in_sizes, int n_in,
                              void* d_out, int out_size, void* d_ws, size_t ws_size,
                              hipStream_t stream) {
    const float* x_in = (const float*)d_in[0];
    const int* edge_index = (const int*)d_in[1];
    const float *cw[5], *cb[5], *pw[5];
    for (int i = 0; i < 5; i++) {
        cw[i] = (const float*)d_in[3 + 3 * i];
        cb[i] = (const float*)d_in[4 + 3 * i];
        pw[i] = (const float*)d_in[5 + 3 * i];
    }
    const float* l1w = (const float*)d_in[18];
    const float* l1b = (const float*)d_in[19];
    const float* l2w = (const float*)d_in[20];
    const float* l2b = (const float*)d_in[21];
    const float* l3w = (const float*)d_in[22];
    const float* l3b = (const float*)d_in[23];
    float* out = (float*)d_out;

    char* w = (char*)d_ws;
    float* xA    = (float*)w; w += (size_t)65536 * DIM * 4;
    float* xB    = (float*)w; w += (size_t)65536 * DIM * 4;
    float* xL    = (float*)w; w += (size_t)65536 * DIM * 4;
    int*   src   = (int*)w;   w += (size_t)ETOT * 4;
    int*   dst   = (int*)w;   w += (size_t)ETOT * 4;
    int2*  epack = (int2*)w;  w += (size_t)ETOT * 8;
    float* deg   = (float*)w; w += (size_t)65536 * 4;
    int*   cnt   = (int*)w;   w += (size_t)65536 * 4;
    int*   eoff  = (int*)w;   w += (size_t)65536 * 4;
    float* dinv  = (float*)w; w += (size_t)65536 * 4;
    float* score = (float*)w; w += (size_t)65536 * 4;
    float* hsum  = (float*)w; w += (size_t)NB * 256 * 4;
    float* invn  = (float*)w; w += 4;

    init_kernel<<<NB, 256, 0, stream>>>(edge_index, src, dst, deg, cnt, hsum);

    const float* xin = x_in;
    for (int i = 0; i < 5; i++) {
        int n = NS_H[i], k = NS_H[i + 1];
        int N = NB * n;

        linear_kernel<<<N / 64, 256, 0, stream>>>(xin, cw[i], cb[i], xL, N);
        scan_scatter_kernel<<<NB, 1024, 0, stream>>>(cnt, deg, dinv, eoff, src, dst, epack,
                                                     n, pw[i], invn);
        int gpb = (n + 7) / 8;
        fused_agg_kernel<<<NB * gpb, 256, 0, stream>>>(xL, epack, eoff, cnt, dinv, pw[i],
                                                       invn, xA, score, n);
        pool_kernel<<<NB, 1024, 0, stream>>>(score, xA, xB, hsum, src, dst, deg, cnt, n, k);

        xin = xB;
    }

    head_kernel<<<NB, 128, 0, stream>>>(hsum, l1w, l1b, l2w, l2b, l3w, l3b, out);
}

// Round 8
// 597.340 us; speedup vs baseline: 10.1877x; 1.1265x over previous
//
#include <hip/hip_runtime.h>
#include <math.h>

#define NB 64
#define DIM 128
#define ETOT 1048576
#define EPG 16384   // edges-per-graph region (ETOT / NB)
#define EPT 16      // edges per thread in 1024-thread per-graph kernels
#define WRS 192     // LDS row stride (floats) for W tile
#define XRS 96      // LDS row stride for x tile

static const int NS_H[6] = {1024, 820, 656, 525, 420, 336};

// ---------------- init: edges->src/dst, histogram, scan, scatter epack, dinv, invn ----------------
__global__ __launch_bounds__(1024) void init_kernel(const int* __restrict__ ei,
                                  int* __restrict__ src, int* __restrict__ dst,
                                  int2* __restrict__ epack, int* __restrict__ eoff,
                                  int* __restrict__ cnt, float* __restrict__ dinv,
                                  float* __restrict__ invn, const float* __restrict__ pw0,
                                  float* __restrict__ hsum) {
    __shared__ int hs[1024], hc[1024], cur[1024];
    __shared__ float dv[1024];
    __shared__ float shf[128];
    int g = blockIdx.x, t = threadIdx.x;
    hs[t] = 0; hc[t] = 0;
    if (t < 256) hsum[g * 256 + t] = 0.f;
    __syncthreads();
    int b0 = g * EPG;
    int sr[EPT], dr[EPT];
#pragma unroll
    for (int q = 0; q < EPT; q++) {
        int e = b0 + q * 1024 + t;
        int s = ei[e], d = ei[ETOT + e];
        sr[q] = s; dr[q] = d;
        src[e] = s; dst[e] = d;
        atomicAdd(&hs[s & 1023], 1);
        atomicAdd(&hc[d & 1023], 1);
    }
    __syncthreads();
    cur[t] = hc[t];
    dv[t] = rsqrtf((float)hs[t] + 1.0f);
    __syncthreads();
    int v = cur[t];
    for (int off = 1; off < 1024; off <<= 1) {
        int u = (t >= off) ? cur[t - off] : 0;
        __syncthreads();
        cur[t] += u;
        __syncthreads();
    }
    int excl = b0 + cur[t] - v;
    eoff[g * 1024 + t] = excl;
    cnt[g * 1024 + t] = hc[t];
    dinv[g * 1024 + t] = dv[t];
    __syncthreads();
    cur[t] = excl;
    __syncthreads();
#pragma unroll
    for (int q = 0; q < EPT; q++) {
        int sl = sr[q] & 1023, dl = dr[q] & 1023;
        int pos = atomicAdd(&cur[dl], 1);
        epack[pos] = make_int2(sr[q], __float_as_int(dv[sl] * dv[dl]));
    }
    if (g == 0) {
        if (t < 128) shf[t] = pw0[t] * pw0[t];
        __syncthreads();
        for (int s = 64; s > 0; s >>= 1) {
            if (t < s) shf[t] += shf[t + s];
            __syncthreads();
        }
        if (t == 0) invn[0] = rsqrtf(shf[0]);
    }
}

// ---------------- linear: y = x @ W.T + b (64n x 128f tile, conflict-free swizzle) ----------------
__global__ __launch_bounds__(256) void linear_kernel(const float* __restrict__ x,
                              const float* __restrict__ W, const float* __restrict__ b,
                              float* __restrict__ y, int N) {
    __shared__ float Wt[32 * WRS];
    __shared__ float xT[32 * XRS];
    int tid = threadIdx.x;
    int base = blockIdx.x * 64;
    int nf = tid & 15;
    int u  = tid >> 4;
    float acc[4][8];
    {
        float bv[8];
#pragma unroll
        for (int f = 0; f < 8; f++) bv[f] = b[u * 8 + f];
#pragma unroll
        for (int i = 0; i < 4; i++)
#pragma unroll
            for (int f = 0; f < 8; f++) acc[i][f] = bv[f];
    }
    for (int kb = 0; kb < 4; kb++) {
        __syncthreads();
#pragma unroll
        for (int q = 0; q < 4; q++) {
            int i = q * 256 + tid;
            int dq = i >> 7;
            int r = i & 127;
            int s = (r >> 3) * 12 + (r & 7);
            float4 wv = *(const float4*)(W + r * 128 + kb * 32 + dq * 4);
            Wt[(dq * 4 + 0) * WRS + s] = wv.x;
            Wt[(dq * 4 + 1) * WRS + s] = wv.y;
            Wt[(dq * 4 + 2) * WRS + s] = wv.z;
            Wt[(dq * 4 + 3) * WRS + s] = wv.w;
        }
#pragma unroll
        for (int q = 0; q < 2; q++) {
            int i = q * 256 + tid;
            int dq = i >> 6;
            int r = i & 63;
            int s = (r >> 3) * 12 + (r & 7);
            float4 xv = *(const float4*)(x + (size_t)(base + r) * DIM + kb * 32 + dq * 4);
            xT[(dq * 4 + 0) * XRS + s] = xv.x;
            xT[(dq * 4 + 1) * XRS + s] = xv.y;
            xT[(dq * 4 + 2) * XRS + s] = xv.z;
            xT[(dq * 4 + 3) * XRS + s] = xv.w;
        }
        __syncthreads();
#pragma unroll 4
        for (int d = 0; d < 32; d++) {
            float4 xv = *(const float4*)&xT[d * XRS + (nf >> 1) * 12 + (nf & 1) * 4];
            float4 wa = *(const float4*)&Wt[d * WRS + u * 12];
            float4 wb = *(const float4*)&Wt[d * WRS + u * 12 + 4];
            float xs[4] = {xv.x, xv.y, xv.z, xv.w};
            float ws[8] = {wa.x, wa.y, wa.z, wa.w, wb.x, wb.y, wb.z, wb.w};
#pragma unroll
            for (int i = 0; i < 4; i++)
#pragma unroll
                for (int f = 0; f < 8; f++)
                    acc[i][f] += xs[i] * ws[f];
        }
    }
#pragma unroll
    for (int i = 0; i < 4; i++) {
        int nd = base + nf * 4 + i;
        float* yp = y + (size_t)nd * DIM + u * 8;
        *(float4*)(yp + 0) = make_float4(acc[i][0], acc[i][1], acc[i][2], acc[i][3]);
        *(float4*)(yp + 4) = make_float4(acc[i][4], acc[i][5], acc[i][6], acc[i][7]);
    }
}

// ---------------- fused aggregate + self + relu + score (packed edges, unroll 4) ----------------
__global__ void fused_agg_kernel(const float* __restrict__ xL, const int2* __restrict__ epack,
                                 const int* __restrict__ eoff, const int* __restrict__ cnt,
                                 const float* __restrict__ dinv,
                                 const float* __restrict__ pw, const float* __restrict__ invn,
                                 float* __restrict__ xA, float* __restrict__ score, int n) {
    int t = threadIdx.x;
    int g = blockIdx.x % NB;
    int chunk = blockIdx.x / NB;
    int ln = chunk * 8 + (t >> 5);
    if (ln >= n) return;
    int node = g * n + ln;
    int lane = t & 31;
    float dsn = dinv[node];
    float4 sv = ((const float4*)(xL + (size_t)node * DIM))[lane];
    float w0 = dsn * dsn;
    float4 a0 = make_float4(sv.x * w0, sv.y * w0, sv.z * w0, sv.w * w0);
    float4 a1 = make_float4(0.f, 0.f, 0.f, 0.f);
    float4 a2 = make_float4(0.f, 0.f, 0.f, 0.f);
    float4 a3 = make_float4(0.f, 0.f, 0.f, 0.f);
    int s0 = eoff[node], s1 = s0 + cnt[node];
    int j = s0;
    for (; j + 3 < s1; j += 4) {
        int2 e0 = epack[j];
        int2 e1 = epack[j + 1];
        int2 e2 = epack[j + 2];
        int2 e3 = epack[j + 3];
        float4 x0 = ((const float4*)(xL + (size_t)e0.x * DIM))[lane];
        float4 x1 = ((const float4*)(xL + (size_t)e1.x * DIM))[lane];
        float4 x2 = ((const float4*)(xL + (size_t)e2.x * DIM))[lane];
        float4 x3 = ((const float4*)(xL + (size_t)e3.x * DIM))[lane];
        float n0 = __int_as_float(e0.y), n1 = __int_as_float(e1.y);
        float n2 = __int_as_float(e2.y), n3 = __int_as_float(e3.y);
        a0.x += n0 * x0.x; a0.y += n0 * x0.y; a0.z += n0 * x0.z; a0.w += n0 * x0.w;
        a1.x += n1 * x1.x; a1.y += n1 * x1.y; a1.z += n1 * x1.z; a1.w += n1 * x1.w;
        a2.x += n2 * x2.x; a2.y += n2 * x2.y; a2.z += n2 * x2.z; a2.w += n2 * x2.w;
        a3.x += n3 * x3.x; a3.y += n3 * x3.y; a3.z += n3 * x3.z; a3.w += n3 * x3.w;
    }
    for (; j < s1; j++) {
        int2 e0 = epack[j];
        float n0 = __int_as_float(e0.y);
        float4 x0 = ((const float4*)(xL + (size_t)e0.x * DIM))[lane];
        a0.x += n0 * x0.x; a0.y += n0 * x0.y; a0.z += n0 * x0.z; a0.w += n0 * x0.w;
    }
    float4 acc = make_float4(fmaxf(a0.x + a1.x + a2.x + a3.x, 0.f),
                             fmaxf(a0.y + a1.y + a2.y + a3.y, 0.f),
                             fmaxf(a0.z + a1.z + a2.z + a3.z, 0.f),
                             fmaxf(a0.w + a1.w + a2.w + a3.w, 0.f));
    ((float4*)(xA + (size_t)node * DIM))[lane] = acc;
    float4 pv = ((const float4*)pw)[lane];
    float dot = acc.x * pv.x + acc.y * pv.y + acc.z * pv.z + acc.w * pv.w;
    for (int off = 16; off >= 1; off >>= 1) dot += __shfl_xor(dot, off, 32);
    if (lane == 0) score[node] = tanhf(dot * invn[0]);
}

// ---------------- pool: sort+newid+gather+readout+remap+count+scan+scatter+dinv+invn ----------------
__global__ __launch_bounds__(1024) void pool_kernel(const float* __restrict__ score,
                              const float* __restrict__ xA, float* __restrict__ xn,
                              float* __restrict__ h, int* __restrict__ src,
                              int* __restrict__ dst, int2* __restrict__ epack,
                              int* __restrict__ eoff, int* __restrict__ cnt,
                              float* __restrict__ dinv, const float* __restrict__ pwN,
                              float* __restrict__ invn, int n, int k) {
    __shared__ float key[1024];
    __shared__ int idx[1024];
    __shared__ int nid[1024];
    __shared__ float4 smax[32][33];
    __shared__ float4 ssum[32][33];
    __shared__ int hs[1024], hc[1024], cur[1024];
    __shared__ float dv[1024];
    __shared__ float shf[128];
    int g = blockIdx.x, t = threadIdx.x;
    // ---- load scores (sentinel -2 beyond n) ----
    if (t < n) { key[t] = score[g * n + t]; idx[t] = t; }
    else       { key[t] = -2.0f;            idx[t] = t; }
    hs[t] = 0; hc[t] = 0;
    __syncthreads();
    // ---- bitonic sort: desc score, ties -> lower idx ----
    for (unsigned ksz = 2; ksz <= 1024; ksz <<= 1) {
        for (unsigned jj = ksz >> 1; jj > 0; jj >>= 1) {
            unsigned i = t, ixj = i ^ jj;
            if (ixj > i) {
                float ka = key[i], kb = key[ixj];
                int ia = idx[i], ib = idx[ixj];
                bool aLess = (ka > kb) || (ka == kb && ia < ib);
                bool up = ((i & ksz) == 0);
                if (up ? !aLess : aLess) {
                    key[i] = kb; key[ixj] = ka; idx[i] = ib; idx[ixj] = ia;
                }
            }
            __syncthreads();
        }
    }
    nid[idx[t]] = (t < (unsigned)k) ? t : -1;
    __syncthreads();
    // ---- gather xn = xA[perm]*s + readout max/mean ----
    int lane4 = t & 31;
    int ch = t >> 5;
    float4 mx = make_float4(-INFINITY, -INFINITY, -INFINITY, -INFINITY);
    float4 sm = make_float4(0.f, 0.f, 0.f, 0.f);
    for (int j = ch; j < k; j += 32) {
        int row = idx[j];
        float sval = key[j];
        float4 v = ((const float4*)(xA + ((size_t)g * n + row) * DIM))[lane4];
        v.x *= sval; v.y *= sval; v.z *= sval; v.w *= sval;
        ((float4*)(xn + ((size_t)g * k + j) * DIM))[lane4] = v;
        mx.x = fmaxf(mx.x, v.x); mx.y = fmaxf(mx.y, v.y);
        mx.z = fmaxf(mx.z, v.z); mx.w = fmaxf(mx.w, v.w);
        sm.x += v.x; sm.y += v.y; sm.z += v.z; sm.w += v.w;
    }
    smax[ch][lane4] = mx;
    ssum[ch][lane4] = sm;
    __syncthreads();
    for (int s = 16; s >= 1; s >>= 1) {
        if (ch < s) {
            float4 a = smax[ch][lane4], bb = smax[ch + s][lane4];
            a.x = fmaxf(a.x, bb.x); a.y = fmaxf(a.y, bb.y);
            a.z = fmaxf(a.z, bb.z); a.w = fmaxf(a.w, bb.w);
            smax[ch][lane4] = a;
            float4 c = ssum[ch][lane4], d = ssum[ch + s][lane4];
            c.x += d.x; c.y += d.y; c.z += d.z; c.w += d.w;
            ssum[ch][lane4] = c;
        }
        __syncthreads();
    }
    if (ch == 0) {
        float4 m = smax[0][lane4];
        float4 s4 = ssum[0][lane4];
        float invk = 1.0f / (float)k;
        int f0 = lane4 * 4;
        float* hp = h + g * 256;
        hp[f0 + 0] += m.x; hp[f0 + 1] += m.y; hp[f0 + 2] += m.z; hp[f0 + 3] += m.w;
        hp[128 + f0 + 0] += s4.x * invk; hp[128 + f0 + 1] += s4.y * invk;
        hp[128 + f0 + 2] += s4.z * invk; hp[128 + f0 + 3] += s4.w * invk;
    }
    // ---- remap edges (held in registers) + next-layer deg/cnt histogram ----
    int b0 = g * EPG, gn = g * n, gk = g * k;
    int sr[EPT], dr[EPT];
#pragma unroll
    for (int q = 0; q < EPT; q++) {
        int e = b0 + q * 1024 + t;
        int s = src[e];
        int s2 = -1, d2 = -1;
        if (s >= 0) {
            s2 = nid[s - gn];
            d2 = nid[dst[e] - gn];
            if (s2 >= 0 && d2 >= 0) {
                src[e] = gk + s2;
                dst[e] = gk + d2;
                atomicAdd(&hs[s2], 1);
                atomicAdd(&hc[d2], 1);
            } else {
                src[e] = -1;
                dst[e] = -1;
                s2 = -1;
            }
        }
        sr[q] = s2; dr[q] = d2;
    }
    __syncthreads();
    // ---- scan hc -> eoff/cursor; dinv for next layer ----
    if (t < k) {
        cur[t] = hc[t];
        dv[t] = rsqrtf((float)hs[t] + 1.0f);
    } else cur[t] = 0;
    __syncthreads();
    int v = cur[t];
    for (int off = 1; off < 1024; off <<= 1) {
        int u = (t >= off) ? cur[t - off] : 0;
        __syncthreads();
        cur[t] += u;
        __syncthreads();
    }
    if (t < k) {
        int excl = b0 + cur[t] - v;
        eoff[gk + t] = excl;
        cnt[gk + t] = hc[t];
        dinv[gk + t] = dv[t];
        cur[t] = excl;
    }
    __syncthreads();
    // ---- scatter packed edges for next layer ----
#pragma unroll
    for (int q = 0; q < EPT; q++) {
        if (sr[q] >= 0) {
            int pos = atomicAdd(&cur[dr[q]], 1);
            epack[pos] = make_int2(gk + sr[q], __float_as_int(dv[sr[q]] * dv[dr[q]]));
        }
    }
    // ---- invn for next layer's pool weight ----
    if (g == 0) {
        if (t < 128) shf[t] = pwN[t] * pwN[t];
        __syncthreads();
        for (int s = 64; s > 0; s >>= 1) {
            if (t < s) shf[t] += shf[t + s];
            __syncthreads();
        }
        if (t == 0) invn[0] = rsqrtf(shf[0]);
    }
}

// ---------------- MLP head + log_softmax ----------------
__global__ void head_kernel(const float* __restrict__ h,
                            const float* __restrict__ l1w, const float* __restrict__ l1b,
                            const float* __restrict__ l2w, const float* __restrict__ l2b,
                            const float* __restrict__ l3w, const float* __restrict__ l3b,
                            float* __restrict__ out) {
    __shared__ float hr[256];
    __shared__ float h1[128];
    __shared__ float h2[64];
    __shared__ float lz[2];
    int g = blockIdx.x, t = threadIdx.x;
    hr[t] = h[g * 256 + t];
    hr[t + 128] = h[g * 256 + 128 + t];
    __syncthreads();
    float acc = l1b[t];
    for (int d = 0; d < 256; d++) acc += hr[d] * l1w[t * 256 + d];
    h1[t] = fmaxf(acc, 0.f);
    __syncthreads();
    if (t < 64) {
        float a2 = l2b[t];
        for (int d = 0; d < 128; d++) a2 += h1[d] * l2w[t * 128 + d];
        h2[t] = fmaxf(a2, 0.f);
    }
    __syncthreads();
    if (t < 2) {
        float a3 = l3b[t];
        for (int d = 0; d < 64; d++) a3 += h2[d] * l3w[t * 64 + d];
        lz[t] = a3;
    }
    __syncthreads();
    if (t < 2) {
        float z0 = lz[0], z1 = lz[1];
        float m = fmaxf(z0, z1);
        float lse = m + logf(expf(z0 - m) + expf(z1 - m));
        out[g * 2 + t] = lz[t] - lse;
    }
}

extern "C" void kernel_launch(void* const* d_in, const int* in_sizes, int n_in,
                              void* d_out, int out_size, void* d_ws, size_t ws_size,
                              hipStream_t stream) {
    const float* x_in = (const float*)d_in[0];
    const int* edge_index = (const int*)d_in[1];
    const float *cw[5], *cb[5], *pw[5];
    for (int i = 0; i < 5; i++) {
        cw[i] = (const float*)d_in[3 + 3 * i];
        cb[i] = (const float*)d_in[4 + 3 * i];
        pw[i] = (const float*)d_in[5 + 3 * i];
    }
    const float* l1w = (const float*)d_in[18];
    const float* l1b = (const float*)d_in[19];
    const float* l2w = (const float*)d_in[20];
    const float* l2b = (const float*)d_in[21];
    const float* l3w = (const float*)d_in[22];
    const float* l3b = (const float*)d_in[23];
    float* out = (float*)d_out;

    char* w = (char*)d_ws;
    float* xA    = (float*)w; w += (size_t)65536 * DIM * 4;
    float* xB    = (float*)w; w += (size_t)65536 * DIM * 4;
    float* xL    = (float*)w; w += (size_t)65536 * DIM * 4;
    int*   src   = (int*)w;   w += (size_t)ETOT * 4;
    int*   dst   = (int*)w;   w += (size_t)ETOT * 4;
    int2*  epack = (int2*)w;  w += (size_t)ETOT * 8;
    int*   cnt   = (int*)w;   w += (size_t)65536 * 4;
    int*   eoff  = (int*)w;   w += (size_t)65536 * 4;
    float* dinv  = (float*)w; w += (size_t)65536 * 4;
    float* score = (float*)w; w += (size_t)65536 * 4;
    float* hsum  = (float*)w; w += (size_t)NB * 256 * 4;
    float* invn  = (float*)w; w += 4;

    init_kernel<<<NB, 1024, 0, stream>>>(edge_index, src, dst, epack, eoff, cnt, dinv,
                                         invn, pw[0], hsum);

    const float* xin = x_in;
    for (int i = 0; i < 5; i++) {
        int n = NS_H[i], k = NS_H[i + 1];
        int N = NB * n;

        linear_kernel<<<N / 64, 256, 0, stream>>>(xin, cw[i], cb[i], xL, N);
        int gpb = (n + 7) / 8;
        fused_agg_kernel<<<NB * gpb, 256, 0, stream>>>(xL, epack, eoff, cnt, dinv, pw[i],
                                                       invn, xA, score, n);
        const float* pwN = (i < 4) ? pw[i + 1] : pw[i];
        pool_kernel<<<NB, 1024, 0, stream>>>(score, xA, xB, hsum, src, dst, epack, eoff,
                                             cnt, dinv, pwN, invn, n, k);

        xin = xB;
    }

    head_kernel<<<NB, 128, 0, stream>>>(hsum, l1w, l1b, l2w, l2b, l3w, l3b, out);
}

// Round 9
// 565.210 us; speedup vs baseline: 10.7668x; 1.0568x over previous
//
#include <hip/hip_runtime.h>
#include <math.h>

#define NB 64
#define DIM 128
#define ETOT 1048576
#define EPG 16384   // edges-per-graph region (ETOT / NB)
#define EPT 16      // edges per thread in 1024-thread per-graph kernels
#define WRS 192     // LDS row stride (floats) for W tile
#define XRS 96      // LDS row stride for x tile

static const int NS_H[6] = {1024, 820, 656, 525, 420, 336};

// ---------------- init: edges->src/dst, histogram, scan, scatter epack, dinv, invn ----------------
__global__ __launch_bounds__(1024) void init_kernel(const int* __restrict__ ei,
                                  int* __restrict__ src, int* __restrict__ dst,
                                  int2* __restrict__ epack, int* __restrict__ eoff,
                                  int* __restrict__ cnt, float* __restrict__ dinv,
                                  float* __restrict__ invn, const float* __restrict__ pw0,
                                  float* __restrict__ hsum) {
    __shared__ int hs[1024], hc[1024], cur[1024];
    __shared__ float dv[1024];
    __shared__ float shf[128];
    __shared__ int wsum[16];
    int g = blockIdx.x, t = threadIdx.x;
    int lane = t & 63, wv = t >> 6;
    hs[t] = 0; hc[t] = 0;
    if (t < 256) hsum[g * 256 + t] = 0.f;
    __syncthreads();
    int b0 = g * EPG;
    int sr[EPT], dr[EPT];
#pragma unroll
    for (int q = 0; q < EPT; q++) {
        int e = b0 + q * 1024 + t;
        int s = ei[e], d = ei[ETOT + e];
        sr[q] = s; dr[q] = d;
        src[e] = s; dst[e] = d;
        atomicAdd(&hs[s & 1023], 1);
        atomicAdd(&hc[d & 1023], 1);
    }
    __syncthreads();
    int v = hc[t];
    dv[t] = rsqrtf((float)hs[t] + 1.0f);
    // two-level exclusive scan of hc
    int s = v;
#pragma unroll
    for (int off = 1; off < 64; off <<= 1) {
        int u = __shfl_up(s, off, 64);
        if (lane >= off) s += u;
    }
    if (lane == 63) wsum[wv] = s;
    __syncthreads();
    if (wv == 0) {
        int ws = (lane < 16) ? wsum[lane] : 0;
#pragma unroll
        for (int off = 1; off < 16; off <<= 1) {
            int u = __shfl_up(ws, off, 64);
            if (lane >= off) ws += u;
        }
        if (lane < 16) wsum[lane] = ws;
    }
    __syncthreads();
    int excl = b0 + s + ((wv > 0) ? wsum[wv - 1] : 0) - v;
    eoff[g * 1024 + t] = excl;
    cnt[g * 1024 + t] = v;
    dinv[g * 1024 + t] = dv[t];
    cur[t] = excl;
    __syncthreads();
#pragma unroll
    for (int q = 0; q < EPT; q++) {
        int sl = sr[q] & 1023, dl = dr[q] & 1023;
        int pos = atomicAdd(&cur[dl], 1);
        epack[pos] = make_int2(sr[q], __float_as_int(dv[sl] * dv[dl]));
    }
    if (g == 0) {
        if (t < 128) shf[t] = pw0[t] * pw0[t];
        __syncthreads();
        for (int q = 64; q > 0; q >>= 1) {
            if (t < q) shf[t] += shf[t + q];
            __syncthreads();
        }
        if (t == 0) invn[0] = rsqrtf(shf[0]);
    }
}

// ---------------- linear: y = x @ W.T + b (64n x 128f tile, conflict-free swizzle) ----------------
__global__ __launch_bounds__(256) void linear_kernel(const float* __restrict__ x,
                              const float* __restrict__ W, const float* __restrict__ b,
                              float* __restrict__ y, int N) {
    __shared__ float Wt[32 * WRS];
    __shared__ float xT[32 * XRS];
    int tid = threadIdx.x;
    int base = blockIdx.x * 64;
    int nf = tid & 15;
    int u  = tid >> 4;
    float acc[4][8];
    {
        float bv[8];
#pragma unroll
        for (int f = 0; f < 8; f++) bv[f] = b[u * 8 + f];
#pragma unroll
        for (int i = 0; i < 4; i++)
#pragma unroll
            for (int f = 0; f < 8; f++) acc[i][f] = bv[f];
    }
    for (int kb = 0; kb < 4; kb++) {
        __syncthreads();
#pragma unroll
        for (int q = 0; q < 4; q++) {
            int i = q * 256 + tid;
            int dq = i >> 7;
            int r = i & 127;
            int s = (r >> 3) * 12 + (r & 7);
            float4 wv = *(const float4*)(W + r * 128 + kb * 32 + dq * 4);
            Wt[(dq * 4 + 0) * WRS + s] = wv.x;
            Wt[(dq * 4 + 1) * WRS + s] = wv.y;
            Wt[(dq * 4 + 2) * WRS + s] = wv.z;
            Wt[(dq * 4 + 3) * WRS + s] = wv.w;
        }
#pragma unroll
        for (int q = 0; q < 2; q++) {
            int i = q * 256 + tid;
            int dq = i >> 6;
            int r = i & 63;
            int s = (r >> 3) * 12 + (r & 7);
            float4 xv = *(const float4*)(x + (size_t)(base + r) * DIM + kb * 32 + dq * 4);
            xT[(dq * 4 + 0) * XRS + s] = xv.x;
            xT[(dq * 4 + 1) * XRS + s] = xv.y;
            xT[(dq * 4 + 2) * XRS + s] = xv.z;
            xT[(dq * 4 + 3) * XRS + s] = xv.w;
        }
        __syncthreads();
#pragma unroll 4
        for (int d = 0; d < 32; d++) {
            float4 xv = *(const float4*)&xT[d * XRS + (nf >> 1) * 12 + (nf & 1) * 4];
            float4 wa = *(const float4*)&Wt[d * WRS + u * 12];
            float4 wb = *(const float4*)&Wt[d * WRS + u * 12 + 4];
            float xs[4] = {xv.x, xv.y, xv.z, xv.w};
            float ws[8] = {wa.x, wa.y, wa.z, wa.w, wb.x, wb.y, wb.z, wb.w};
#pragma unroll
            for (int i = 0; i < 4; i++)
#pragma unroll
                for (int f = 0; f < 8; f++)
                    acc[i][f] += xs[i] * ws[f];
        }
    }
#pragma unroll
    for (int i = 0; i < 4; i++) {
        int nd = base + nf * 4 + i;
        float* yp = y + (size_t)nd * DIM + u * 8;
        *(float4*)(yp + 0) = make_float4(acc[i][0], acc[i][1], acc[i][2], acc[i][3]);
        *(float4*)(yp + 4) = make_float4(acc[i][4], acc[i][5], acc[i][6], acc[i][7]);
    }
}

// ---------------- fused aggregate + self + relu + score (packed edges, unroll 4) ----------------
__global__ void fused_agg_kernel(const float* __restrict__ xL, const int2* __restrict__ epack,
                                 const int* __restrict__ eoff, const int* __restrict__ cnt,
                                 const float* __restrict__ dinv,
                                 const float* __restrict__ pw, const float* __restrict__ invn,
                                 float* __restrict__ xA, float* __restrict__ score, int n) {
    int t = threadIdx.x;
    int g = blockIdx.x % NB;
    int chunk = blockIdx.x / NB;
    int ln = chunk * 8 + (t >> 5);
    if (ln >= n) return;
    int node = g * n + ln;
    int lane = t & 31;
    float dsn = dinv[node];
    float4 sv = ((const float4*)(xL + (size_t)node * DIM))[lane];
    float w0 = dsn * dsn;
    float4 a0 = make_float4(sv.x * w0, sv.y * w0, sv.z * w0, sv.w * w0);
    float4 a1 = make_float4(0.f, 0.f, 0.f, 0.f);
    float4 a2 = make_float4(0.f, 0.f, 0.f, 0.f);
    float4 a3 = make_float4(0.f, 0.f, 0.f, 0.f);
    int s0 = eoff[node], s1 = s0 + cnt[node];
    int j = s0;
    for (; j + 3 < s1; j += 4) {
        int2 e0 = epack[j];
        int2 e1 = epack[j + 1];
        int2 e2 = epack[j + 2];
        int2 e3 = epack[j + 3];
        float4 x0 = ((const float4*)(xL + (size_t)e0.x * DIM))[lane];
        float4 x1 = ((const float4*)(xL + (size_t)e1.x * DIM))[lane];
        float4 x2 = ((const float4*)(xL + (size_t)e2.x * DIM))[lane];
        float4 x3 = ((const float4*)(xL + (size_t)e3.x * DIM))[lane];
        float n0 = __int_as_float(e0.y), n1 = __int_as_float(e1.y);
        float n2 = __int_as_float(e2.y), n3 = __int_as_float(e3.y);
        a0.x += n0 * x0.x; a0.y += n0 * x0.y; a0.z += n0 * x0.z; a0.w += n0 * x0.w;
        a1.x += n1 * x1.x; a1.y += n1 * x1.y; a1.z += n1 * x1.z; a1.w += n1 * x1.w;
        a2.x += n2 * x2.x; a2.y += n2 * x2.y; a2.z += n2 * x2.z; a2.w += n2 * x2.w;
        a3.x += n3 * x3.x; a3.y += n3 * x3.y; a3.z += n3 * x3.z; a3.w += n3 * x3.w;
    }
    for (; j < s1; j++) {
        int2 e0 = epack[j];
        float n0 = __int_as_float(e0.y);
        float4 x0 = ((const float4*)(xL + (size_t)e0.x * DIM))[lane];
        a0.x += n0 * x0.x; a0.y += n0 * x0.y; a0.z += n0 * x0.z; a0.w += n0 * x0.w;
    }
    float4 acc = make_float4(fmaxf(a0.x + a1.x + a2.x + a3.x, 0.f),
                             fmaxf(a0.y + a1.y + a2.y + a3.y, 0.f),
                             fmaxf(a0.z + a1.z + a2.z + a3.z, 0.f),
                             fmaxf(a0.w + a1.w + a2.w + a3.w, 0.f));
    ((float4*)(xA + (size_t)node * DIM))[lane] = acc;
    float4 pv = ((const float4*)pw)[lane];
    float dot = acc.x * pv.x + acc.y * pv.y + acc.z * pv.z + acc.w * pv.w;
    for (int off = 16; off >= 1; off >>= 1) dot += __shfl_xor(dot, off, 32);
    if (lane == 0) score[node] = tanhf(dot * invn[0]);
}

// ---------------- pool: hybrid shuffle/LDS bitonic sort + gather/readout + remap + CSR ----------------
__global__ __launch_bounds__(1024) void pool_kernel(const float* __restrict__ score,
                              const float* __restrict__ xA, float* __restrict__ xn,
                              float* __restrict__ h, int* __restrict__ src,
                              int* __restrict__ dst, int2* __restrict__ epack,
                              int* __restrict__ eoff, int* __restrict__ cnt,
                              float* __restrict__ dinv, const float* __restrict__ pwN,
                              float* __restrict__ invn, int n, int k) {
    __shared__ float keyS[2][1024];
    __shared__ int idxS[2][1024];
    __shared__ int nid[1024];
    __shared__ float4 smax[32][33];
    __shared__ float4 ssum[32][33];
    __shared__ int hs[1024], hc[1024], cur[1024];
    __shared__ float dv[1024];
    __shared__ float shf[128];
    __shared__ int wsum[16];
    int g = blockIdx.x, t = threadIdx.x;
    int lane = t & 63, wv = t >> 6;
    // ---- register-resident element (sentinel -2 beyond n) ----
    float k_r = (t < n) ? score[g * n + t] : -2.0f;
    int i_r = t;
    hs[t] = 0; hc[t] = 0;
    // ---- bitonic sort: shuffle for stride<64, LDS (double-buffered) otherwise ----
    int par = 0;
    for (unsigned ksz = 2; ksz <= 1024; ksz <<= 1) {
        for (unsigned jj = ksz >> 1; jj > 0; jj >>= 1) {
            float kq; int iq;
            if (jj >= 64) {
                keyS[par][t] = k_r; idxS[par][t] = i_r;
                __syncthreads();
                kq = keyS[par][t ^ jj]; iq = idxS[par][t ^ jj];
                par ^= 1;
            } else {
                kq = __shfl_xor(k_r, (int)jj, 64);
                iq = __shfl_xor(i_r, (int)jj, 64);
            }
            bool mineFirst = (k_r > kq) || (k_r == kq && i_r < iq);
            bool up = ((t & ksz) == 0);
            bool iAmLower = ((t & jj) == 0);
            bool keepMine = (iAmLower == up) ? mineFirst : !mineFirst;
            if (!keepMine) { k_r = kq; i_r = iq; }
        }
    }
    keyS[0][t] = k_r; idxS[0][t] = i_r;
    nid[i_r] = (t < (unsigned)k) ? t : -1;
    __syncthreads();
    // ---- gather xn = xA[perm]*s + readout max/mean ----
    int lane4 = t & 31;
    int ch = t >> 5;
    float4 mx = make_float4(-INFINITY, -INFINITY, -INFINITY, -INFINITY);
    float4 sm = make_float4(0.f, 0.f, 0.f, 0.f);
    for (int j = ch; j < k; j += 32) {
        int row = idxS[0][j];
        float sval = keyS[0][j];
        float4 vv = ((const float4*)(xA + ((size_t)g * n + row) * DIM))[lane4];
        vv.x *= sval; vv.y *= sval; vv.z *= sval; vv.w *= sval;
        ((float4*)(xn + ((size_t)g * k + j) * DIM))[lane4] = vv;
        mx.x = fmaxf(mx.x, vv.x); mx.y = fmaxf(mx.y, vv.y);
        mx.z = fmaxf(mx.z, vv.z); mx.w = fmaxf(mx.w, vv.w);
        sm.x += vv.x; sm.y += vv.y; sm.z += vv.z; sm.w += vv.w;
    }
    smax[ch][lane4] = mx;
    ssum[ch][lane4] = sm;
    __syncthreads();
    for (int s = 16; s >= 1; s >>= 1) {
        if (ch < s) {
            float4 a = smax[ch][lane4], bb = smax[ch + s][lane4];
            a.x = fmaxf(a.x, bb.x); a.y = fmaxf(a.y, bb.y);
            a.z = fmaxf(a.z, bb.z); a.w = fmaxf(a.w, bb.w);
            smax[ch][lane4] = a;
            float4 c = ssum[ch][lane4], d = ssum[ch + s][lane4];
            c.x += d.x; c.y += d.y; c.z += d.z; c.w += d.w;
            ssum[ch][lane4] = c;
        }
        __syncthreads();
    }
    if (ch == 0) {
        float4 m = smax[0][lane4];
        float4 s4 = ssum[0][lane4];
        float invk = 1.0f / (float)k;
        int f0 = lane4 * 4;
        float* hp = h + g * 256;
        hp[f0 + 0] += m.x; hp[f0 + 1] += m.y; hp[f0 + 2] += m.z; hp[f0 + 3] += m.w;
        hp[128 + f0 + 0] += s4.x * invk; hp[128 + f0 + 1] += s4.y * invk;
        hp[128 + f0 + 2] += s4.z * invk; hp[128 + f0 + 3] += s4.w * invk;
    }
    // ---- remap edges (registers) + next-layer deg/cnt histogram ----
    int b0 = g * EPG, gn = g * n, gk = g * k;
    int sr[EPT], dr[EPT];
#pragma unroll
    for (int q = 0; q < EPT; q++) {
        int e = b0 + q * 1024 + t;
        int s = src[e];
        int s2 = -1, d2 = -1;
        if (s >= 0) {
            s2 = nid[s - gn];
            d2 = nid[dst[e] - gn];
            if (s2 >= 0 && d2 >= 0) {
                src[e] = gk + s2;
                dst[e] = gk + d2;
                atomicAdd(&hs[s2], 1);
                atomicAdd(&hc[d2], 1);
            } else {
                src[e] = -1;
                dst[e] = -1;
                s2 = -1;
            }
        }
        sr[q] = s2; dr[q] = d2;
    }
    __syncthreads();
    // ---- two-level exclusive scan of hc; dinv for next layer ----
    int v = (t < k) ? hc[t] : 0;
    if (t < k) dv[t] = rsqrtf((float)hs[t] + 1.0f);
    int s = v;
#pragma unroll
    for (int off = 1; off < 64; off <<= 1) {
        int u = __shfl_up(s, off, 64);
        if (lane >= off) s += u;
    }
    if (lane == 63) wsum[wv] = s;
    __syncthreads();
    if (wv == 0) {
        int ws = (lane < 16) ? wsum[lane] : 0;
#pragma unroll
        for (int off = 1; off < 16; off <<= 1) {
            int u = __shfl_up(ws, off, 64);
            if (lane >= off) ws += u;
        }
        if (lane < 16) wsum[lane] = ws;
    }
    __syncthreads();
    if (t < k) {
        int excl = b0 + s + ((wv > 0) ? wsum[wv - 1] : 0) - v;
        eoff[gk + t] = excl;
        cnt[gk + t] = v;
        dinv[gk + t] = dv[t];
        cur[t] = excl;
    }
    __syncthreads();
    // ---- scatter packed edges for next layer ----
#pragma unroll
    for (int q = 0; q < EPT; q++) {
        if (sr[q] >= 0) {
            int pos = atomicAdd(&cur[dr[q]], 1);
            epack[pos] = make_int2(gk + sr[q], __float_as_int(dv[sr[q]] * dv[dr[q]]));
        }
    }
    // ---- invn for next layer's pool weight ----
    if (g == 0) {
        if (t < 128) shf[t] = pwN[t] * pwN[t];
        __syncthreads();
        for (int q = 64; q > 0; q >>= 1) {
            if (t < q) shf[t] += shf[t + q];
            __syncthreads();
        }
        if (t == 0) invn[0] = rsqrtf(shf[0]);
    }
}

// ---------------- MLP head + log_softmax ----------------
__global__ void head_kernel(const float* __restrict__ h,
                            const float* __restrict__ l1w, const float* __restrict__ l1b,
                            const float* __restrict__ l2w, const float* __restrict__ l2b,
                            const float* __restrict__ l3w, const float* __restrict__ l3b,
                            float* __restrict__ out) {
    __shared__ float hr[256];
    __shared__ float h1[128];
    __shared__ float h2[64];
    __shared__ float lz[2];
    int g = blockIdx.x, t = threadIdx.x;
    hr[t] = h[g * 256 + t];
    hr[t + 128] = h[g * 256 + 128 + t];
    __syncthreads();
    float acc = l1b[t];
    for (int d = 0; d < 256; d++) acc += hr[d] * l1w[t * 256 + d];
    h1[t] = fmaxf(acc, 0.f);
    __syncthreads();
    if (t < 64) {
        float a2 = l2b[t];
        for (int d = 0; d < 128; d++) a2 += h1[d] * l2w[t * 128 + d];
        h2[t] = fmaxf(a2, 0.f);
    }
    __syncthreads();
    if (t < 2) {
        float a3 = l3b[t];
        for (int d = 0; d < 64; d++) a3 += h2[d] * l3w[t * 64 + d];
        lz[t] = a3;
    }
    __syncthreads();
    if (t < 2) {
        float z0 = lz[0], z1 = lz[1];
        float m = fmaxf(z0, z1);
        float lse = m + logf(expf(z0 - m) + expf(z1 - m));
        out[g * 2 + t] = lz[t] - lse;
    }
}

extern "C" void kernel_launch(void* const* d_in, const int* in_sizes, int n_in,
                              void* d_out, int out_size, void* d_ws, size_t ws_size,
                              hipStream_t stream) {
    const float* x_in = (const float*)d_in[0];
    const int* edge_index = (const int*)d_in[1];
    const float *cw[5], *cb[5], *pw[5];
    for (int i = 0; i < 5; i++) {
        cw[i] = (const float*)d_in[3 + 3 * i];
        cb[i] = (const float*)d_in[4 + 3 * i];
        pw[i] = (const float*)d_in[5 + 3 * i];
    }
    const float* l1w = (const float*)d_in[18];
    const float* l1b = (const float*)d_in[19];
    const float* l2w = (const float*)d_in[20];
    const float* l2b = (const float*)d_in[21];
    const float* l3w = (const float*)d_in[22];
    const float* l3b = (const float*)d_in[23];
    float* out = (float*)d_out;

    char* w = (char*)d_ws;
    float* xA    = (float*)w; w += (size_t)65536 * DIM * 4;
    float* xB    = (float*)w; w += (size_t)65536 * DIM * 4;
    float* xL    = (float*)w; w += (size_t)65536 * DIM * 4;
    int*   src   = (int*)w;   w += (size_t)ETOT * 4;
    int*   dst   = (int*)w;   w += (size_t)ETOT * 4;
    int2*  epack = (int2*)w;  w += (size_t)ETOT * 8;
    int*   cnt   = (int*)w;   w += (size_t)65536 * 4;
    int*   eoff  = (int*)w;   w += (size_t)65536 * 4;
    float* dinv  = (float*)w; w += (size_t)65536 * 4;
    float* score = (float*)w; w += (size_t)65536 * 4;
    float* hsum  = (float*)w; w += (size_t)NB * 256 * 4;
    float* invn  = (float*)w; w += 4;

    init_kernel<<<NB, 1024, 0, stream>>>(edge_index, src, dst, epack, eoff, cnt, dinv,
                                         invn, pw[0], hsum);

    const float* xin = x_in;
    for (int i = 0; i < 5; i++) {
        int n = NS_H[i], k = NS_H[i + 1];
        int N = NB * n;

        linear_kernel<<<N / 64, 256, 0, stream>>>(xin, cw[i], cb[i], xL, N);
        int gpb = (n + 7) / 8;
        fused_agg_kernel<<<NB * gpb, 256, 0, stream>>>(xL, epack, eoff, cnt, dinv, pw[i],
                                                       invn, xA, score, n);
        const float* pwN = (i < 4) ? pw[i + 1] : pw[i];
        pool_kernel<<<NB, 1024, 0, stream>>>(score, xA, xB, hsum, src, dst, epack, eoff,
                                             cnt, dinv, pwN, invn, n, k);

        xin = xB;
    }

    head_kernel<<<NB, 128, 0, stream>>>(hsum, l1w, l1b, l2w, l2b, l3w, l3b, out);
}

// Round 10
// 557.236 us; speedup vs baseline: 10.9209x; 1.0143x over previous
//
#include <hip/hip_runtime.h>
#include <math.h>

#define NB 64
#define DIM 128
#define ETOT 1048576
#define EPG 16384   // edges-per-graph region (ETOT / NB)
#define EPT 16      // edges per thread in 1024-thread per-graph kernels
#define WRS 192     // LDS row stride (floats) for W tile
#define XRS 96      // LDS row stride for x tile

static const int NS_H[6] = {1024, 820, 656, 525, 420, 336};

// ---------------- init: edges->src/dst, histogram, scan, scatter epack, dinv, invn ----------------
__global__ __launch_bounds__(1024) void init_kernel(const int* __restrict__ ei,
                                  int* __restrict__ src, int* __restrict__ dst,
                                  int2* __restrict__ epack, int* __restrict__ eoff,
                                  int* __restrict__ cnt, float* __restrict__ dinv,
                                  float* __restrict__ invn, const float* __restrict__ pw0,
                                  float* __restrict__ hsum) {
    __shared__ int hs[1024], hc[1024], cur[1024];
    __shared__ float dv[1024];
    __shared__ float shf[128];
    __shared__ int wsum[16];
    int g = blockIdx.x, t = threadIdx.x;
    int lane = t & 63, wv = t >> 6;
    hs[t] = 0; hc[t] = 0;
    if (t < 256) hsum[g * 256 + t] = 0.f;
    __syncthreads();
    int b0 = g * EPG;
    int sr[EPT], dr[EPT];
#pragma unroll
    for (int q = 0; q < EPT; q++) {
        int e = b0 + q * 1024 + t;
        int s = ei[e], d = ei[ETOT + e];
        sr[q] = s; dr[q] = d;
        src[e] = s; dst[e] = d;
        atomicAdd(&hs[s & 1023], 1);
        atomicAdd(&hc[d & 1023], 1);
    }
    __syncthreads();
    int v = hc[t];
    dv[t] = rsqrtf((float)hs[t] + 1.0f);
    int s = v;
#pragma unroll
    for (int off = 1; off < 64; off <<= 1) {
        int u = __shfl_up(s, off, 64);
        if (lane >= off) s += u;
    }
    if (lane == 63) wsum[wv] = s;
    __syncthreads();
    if (wv == 0) {
        int ws = (lane < 16) ? wsum[lane] : 0;
#pragma unroll
        for (int off = 1; off < 16; off <<= 1) {
            int u = __shfl_up(ws, off, 64);
            if (lane >= off) ws += u;
        }
        if (lane < 16) wsum[lane] = ws;
    }
    __syncthreads();
    int excl = b0 + s + ((wv > 0) ? wsum[wv - 1] : 0) - v;
    eoff[g * 1024 + t] = excl;
    cnt[g * 1024 + t] = v;
    dinv[g * 1024 + t] = dv[t];
    cur[t] = excl;
    __syncthreads();
#pragma unroll
    for (int q = 0; q < EPT; q++) {
        int sl = sr[q] & 1023, dl = dr[q] & 1023;
        int pos = atomicAdd(&cur[dl], 1);
        epack[pos] = make_int2(sr[q], __float_as_int(dv[sl] * dv[dl]));
    }
    if (g == 0) {
        if (t < 128) shf[t] = pw0[t] * pw0[t];
        __syncthreads();
        for (int q = 64; q > 0; q >>= 1) {
            if (t < q) shf[t] += shf[t + q];
            __syncthreads();
        }
        if (t == 0) invn[0] = rsqrtf(shf[0]);
    }
}

// ---------------- linear: y = x @ W.T + b (64n x 128f tile, conflict-free swizzle) ----------------
__global__ __launch_bounds__(256) void linear_kernel(const float* __restrict__ x,
                              const float* __restrict__ W, const float* __restrict__ b,
                              float* __restrict__ y, int N) {
    __shared__ float Wt[32 * WRS];
    __shared__ float xT[32 * XRS];
    int tid = threadIdx.x;
    int base = blockIdx.x * 64;
    int nf = tid & 15;
    int u  = tid >> 4;
    float acc[4][8];
    {
        float bv[8];
#pragma unroll
        for (int f = 0; f < 8; f++) bv[f] = b[u * 8 + f];
#pragma unroll
        for (int i = 0; i < 4; i++)
#pragma unroll
            for (int f = 0; f < 8; f++) acc[i][f] = bv[f];
    }
    for (int kb = 0; kb < 4; kb++) {
        __syncthreads();
#pragma unroll
        for (int q = 0; q < 4; q++) {
            int i = q * 256 + tid;
            int dq = i >> 7;
            int r = i & 127;
            int s = (r >> 3) * 12 + (r & 7);
            float4 wv = *(const float4*)(W + r * 128 + kb * 32 + dq * 4);
            Wt[(dq * 4 + 0) * WRS + s] = wv.x;
            Wt[(dq * 4 + 1) * WRS + s] = wv.y;
            Wt[(dq * 4 + 2) * WRS + s] = wv.z;
            Wt[(dq * 4 + 3) * WRS + s] = wv.w;
        }
#pragma unroll
        for (int q = 0; q < 2; q++) {
            int i = q * 256 + tid;
            int dq = i >> 6;
            int r = i & 63;
            int s = (r >> 3) * 12 + (r & 7);
            float4 xv = *(const float4*)(x + (size_t)(base + r) * DIM + kb * 32 + dq * 4);
            xT[(dq * 4 + 0) * XRS + s] = xv.x;
            xT[(dq * 4 + 1) * XRS + s] = xv.y;
            xT[(dq * 4 + 2) * XRS + s] = xv.z;
            xT[(dq * 4 + 3) * XRS + s] = xv.w;
        }
        __syncthreads();
#pragma unroll 4
        for (int d = 0; d < 32; d++) {
            float4 xv = *(const float4*)&xT[d * XRS + (nf >> 1) * 12 + (nf & 1) * 4];
            float4 wa = *(const float4*)&Wt[d * WRS + u * 12];
            float4 wb = *(const float4*)&Wt[d * WRS + u * 12 + 4];
            float xs[4] = {xv.x, xv.y, xv.z, xv.w};
            float ws[8] = {wa.x, wa.y, wa.z, wa.w, wb.x, wb.y, wb.z, wb.w};
#pragma unroll
            for (int i = 0; i < 4; i++)
#pragma unroll
                for (int f = 0; f < 8; f++)
                    acc[i][f] += xs[i] * ws[f];
        }
    }
#pragma unroll
    for (int i = 0; i < 4; i++) {
        int nd = base + nf * 4 + i;
        float* yp = y + (size_t)nd * DIM + u * 8;
        *(float4*)(yp + 0) = make_float4(acc[i][0], acc[i][1], acc[i][2], acc[i][3]);
        *(float4*)(yp + 4) = make_float4(acc[i][4], acc[i][5], acc[i][6], acc[i][7]);
    }
}

// ---------------- fused aggregate + self + relu + score (packed edges, unroll 8) ----------------
__global__ void fused_agg_kernel(const float* __restrict__ xL, const int2* __restrict__ epack,
                                 const int* __restrict__ eoff, const int* __restrict__ cnt,
                                 const float* __restrict__ dinv,
                                 const float* __restrict__ pw, const float* __restrict__ invn,
                                 float* __restrict__ xA, float* __restrict__ score, int n) {
    int t = threadIdx.x;
    int g = blockIdx.x % NB;
    int chunk = blockIdx.x / NB;
    int ln = chunk * 8 + (t >> 5);
    if (ln >= n) return;
    int node = g * n + ln;
    int lane = t & 31;
    float dsn = dinv[node];
    float4 sv = ((const float4*)(xL + (size_t)node * DIM))[lane];
    float w0 = dsn * dsn;
    float4 a0 = make_float4(sv.x * w0, sv.y * w0, sv.z * w0, sv.w * w0);
    float4 a1 = make_float4(0.f, 0.f, 0.f, 0.f);
    float4 a2 = make_float4(0.f, 0.f, 0.f, 0.f);
    float4 a3 = make_float4(0.f, 0.f, 0.f, 0.f);
    int s0 = eoff[node], s1 = s0 + cnt[node];
    int j = s0;
    for (; j + 7 < s1; j += 8) {
        int2 e0 = epack[j],     e1 = epack[j + 1], e2 = epack[j + 2], e3 = epack[j + 3];
        int2 e4 = epack[j + 4], e5 = epack[j + 5], e6 = epack[j + 6], e7 = epack[j + 7];
        float4 x0 = ((const float4*)(xL + (size_t)e0.x * DIM))[lane];
        float4 x1 = ((const float4*)(xL + (size_t)e1.x * DIM))[lane];
        float4 x2 = ((const float4*)(xL + (size_t)e2.x * DIM))[lane];
        float4 x3 = ((const float4*)(xL + (size_t)e3.x * DIM))[lane];
        float4 x4 = ((const float4*)(xL + (size_t)e4.x * DIM))[lane];
        float4 x5 = ((const float4*)(xL + (size_t)e5.x * DIM))[lane];
        float4 x6 = ((const float4*)(xL + (size_t)e6.x * DIM))[lane];
        float4 x7 = ((const float4*)(xL + (size_t)e7.x * DIM))[lane];
        float n0 = __int_as_float(e0.y), n1 = __int_as_float(e1.y);
        float n2 = __int_as_float(e2.y), n3 = __int_as_float(e3.y);
        float n4 = __int_as_float(e4.y), n5 = __int_as_float(e5.y);
        float n6 = __int_as_float(e6.y), n7 = __int_as_float(e7.y);
        a0.x += n0 * x0.x; a0.y += n0 * x0.y; a0.z += n0 * x0.z; a0.w += n0 * x0.w;
        a1.x += n1 * x1.x; a1.y += n1 * x1.y; a1.z += n1 * x1.z; a1.w += n1 * x1.w;
        a2.x += n2 * x2.x; a2.y += n2 * x2.y; a2.z += n2 * x2.z; a2.w += n2 * x2.w;
        a3.x += n3 * x3.x; a3.y += n3 * x3.y; a3.z += n3 * x3.z; a3.w += n3 * x3.w;
        a0.x += n4 * x4.x; a0.y += n4 * x4.y; a0.z += n4 * x4.z; a0.w += n4 * x4.w;
        a1.x += n5 * x5.x; a1.y += n5 * x5.y; a1.z += n5 * x5.z; a1.w += n5 * x5.w;
        a2.x += n6 * x6.x; a2.y += n6 * x6.y; a2.z += n6 * x6.z; a2.w += n6 * x6.w;
        a3.x += n7 * x7.x; a3.y += n7 * x7.y; a3.z += n7 * x7.z; a3.w += n7 * x7.w;
    }
    for (; j + 3 < s1; j += 4) {
        int2 e0 = epack[j], e1 = epack[j + 1], e2 = epack[j + 2], e3 = epack[j + 3];
        float4 x0 = ((const float4*)(xL + (size_t)e0.x * DIM))[lane];
        float4 x1 = ((const float4*)(xL + (size_t)e1.x * DIM))[lane];
        float4 x2 = ((const float4*)(xL + (size_t)e2.x * DIM))[lane];
        float4 x3 = ((const float4*)(xL + (size_t)e3.x * DIM))[lane];
        float n0 = __int_as_float(e0.y), n1 = __int_as_float(e1.y);
        float n2 = __int_as_float(e2.y), n3 = __int_as_float(e3.y);
        a0.x += n0 * x0.x; a0.y += n0 * x0.y; a0.z += n0 * x0.z; a0.w += n0 * x0.w;
        a1.x += n1 * x1.x; a1.y += n1 * x1.y; a1.z += n1 * x1.z; a1.w += n1 * x1.w;
        a2.x += n2 * x2.x; a2.y += n2 * x2.y; a2.z += n2 * x2.z; a2.w += n2 * x2.w;
        a3.x += n3 * x3.x; a3.y += n3 * x3.y; a3.z += n3 * x3.z; a3.w += n3 * x3.w;
    }
    for (; j < s1; j++) {
        int2 e0 = epack[j];
        float n0 = __int_as_float(e0.y);
        float4 x0 = ((const float4*)(xL + (size_t)e0.x * DIM))[lane];
        a0.x += n0 * x0.x; a0.y += n0 * x0.y; a0.z += n0 * x0.z; a0.w += n0 * x0.w;
    }
    float4 acc = make_float4(fmaxf(a0.x + a1.x + a2.x + a3.x, 0.f),
                             fmaxf(a0.y + a1.y + a2.y + a3.y, 0.f),
                             fmaxf(a0.z + a1.z + a2.z + a3.z, 0.f),
                             fmaxf(a0.w + a1.w + a2.w + a3.w, 0.f));
    ((float4*)(xA + (size_t)node * DIM))[lane] = acc;
    float4 pv = ((const float4*)pw)[lane];
    float dot = acc.x * pv.x + acc.y * pv.y + acc.z * pv.z + acc.w * pv.w;
    for (int off = 16; off >= 1; off >>= 1) dot += __shfl_xor(dot, off, 32);
    if (lane == 0) score[node] = tanhf(dot * invn[0]);
}

// ---------------- pool: sort + gather/readout (+ CSR rebuild | inline head on last) ----------------
__global__ __launch_bounds__(1024) void pool_kernel(const float* __restrict__ score,
                              const float* __restrict__ xA, float* __restrict__ xn,
                              float* __restrict__ h, int* __restrict__ src,
                              int* __restrict__ dst, int2* __restrict__ epack,
                              int* __restrict__ eoff, int* __restrict__ cnt,
                              float* __restrict__ dinv, const float* __restrict__ pwN,
                              float* __restrict__ invn, int n, int k, int last,
                              const float* __restrict__ l1w, const float* __restrict__ l1b,
                              const float* __restrict__ l2w, const float* __restrict__ l2b,
                              const float* __restrict__ l3w, const float* __restrict__ l3b,
                              float* __restrict__ out) {
    __shared__ float keyS[2][1024];
    __shared__ int idxS[2][1024];
    __shared__ int nid[1024];
    __shared__ float4 smax[32][33];
    __shared__ float4 ssum[32][33];
    __shared__ int hs[1024], hc[1024], cur[1024];
    __shared__ float dv[1024];
    __shared__ float shf[128];
    __shared__ int wsum[16];
    __shared__ float hr[256], h1[128], h2[64], lz[2];
    int g = blockIdx.x, t = threadIdx.x;
    int lane = t & 63, wv = t >> 6;
    float k_r = (t < n) ? score[g * n + t] : -2.0f;
    int i_r = t;
    hs[t] = 0; hc[t] = 0;
    int par = 0;
    for (unsigned ksz = 2; ksz <= 1024; ksz <<= 1) {
        for (unsigned jj = ksz >> 1; jj > 0; jj >>= 1) {
            float kq; int iq;
            if (jj >= 64) {
                keyS[par][t] = k_r; idxS[par][t] = i_r;
                __syncthreads();
                kq = keyS[par][t ^ jj]; iq = idxS[par][t ^ jj];
                par ^= 1;
            } else {
                kq = __shfl_xor(k_r, (int)jj, 64);
                iq = __shfl_xor(i_r, (int)jj, 64);
            }
            bool mineFirst = (k_r > kq) || (k_r == kq && i_r < iq);
            bool up = ((t & ksz) == 0);
            bool iAmLower = ((t & jj) == 0);
            bool keepMine = (iAmLower == up) ? mineFirst : !mineFirst;
            if (!keepMine) { k_r = kq; i_r = iq; }
        }
    }
    keyS[0][t] = k_r; idxS[0][t] = i_r;
    nid[i_r] = (t < (unsigned)k) ? t : -1;
    __syncthreads();
    // ---- gather xn = xA[perm]*s + readout max/mean ----
    int lane4 = t & 31;
    int ch = t >> 5;
    float4 mx = make_float4(-INFINITY, -INFINITY, -INFINITY, -INFINITY);
    float4 sm = make_float4(0.f, 0.f, 0.f, 0.f);
    for (int j = ch; j < k; j += 32) {
        int row = idxS[0][j];
        float sval = keyS[0][j];
        float4 vv = ((const float4*)(xA + ((size_t)g * n + row) * DIM))[lane4];
        vv.x *= sval; vv.y *= sval; vv.z *= sval; vv.w *= sval;
        if (!last) ((float4*)(xn + ((size_t)g * k + j) * DIM))[lane4] = vv;
        mx.x = fmaxf(mx.x, vv.x); mx.y = fmaxf(mx.y, vv.y);
        mx.z = fmaxf(mx.z, vv.z); mx.w = fmaxf(mx.w, vv.w);
        sm.x += vv.x; sm.y += vv.y; sm.z += vv.z; sm.w += vv.w;
    }
    smax[ch][lane4] = mx;
    ssum[ch][lane4] = sm;
    __syncthreads();
    for (int s = 16; s >= 1; s >>= 1) {
        if (ch < s) {
            float4 a = smax[ch][lane4], bb = smax[ch + s][lane4];
            a.x = fmaxf(a.x, bb.x); a.y = fmaxf(a.y, bb.y);
            a.z = fmaxf(a.z, bb.z); a.w = fmaxf(a.w, bb.w);
            smax[ch][lane4] = a;
            float4 c = ssum[ch][lane4], d = ssum[ch + s][lane4];
            c.x += d.x; c.y += d.y; c.z += d.z; c.w += d.w;
            ssum[ch][lane4] = c;
        }
        __syncthreads();
    }
    if (ch == 0) {
        float4 m = smax[0][lane4];
        float4 s4 = ssum[0][lane4];
        float invk = 1.0f / (float)k;
        int f0 = lane4 * 4;
        if (!last) {
            float* hp = h + g * 256;
            hp[f0 + 0] += m.x; hp[f0 + 1] += m.y; hp[f0 + 2] += m.z; hp[f0 + 3] += m.w;
            hp[128 + f0 + 0] += s4.x * invk; hp[128 + f0 + 1] += s4.y * invk;
            hp[128 + f0 + 2] += s4.z * invk; hp[128 + f0 + 3] += s4.w * invk;
        } else {
            const float* hp = h + g * 256;
            hr[f0 + 0] = hp[f0 + 0] + m.x; hr[f0 + 1] = hp[f0 + 1] + m.y;
            hr[f0 + 2] = hp[f0 + 2] + m.z; hr[f0 + 3] = hp[f0 + 3] + m.w;
            hr[128 + f0 + 0] = hp[128 + f0 + 0] + s4.x * invk;
            hr[128 + f0 + 1] = hp[128 + f0 + 1] + s4.y * invk;
            hr[128 + f0 + 2] = hp[128 + f0 + 2] + s4.z * invk;
            hr[128 + f0 + 3] = hp[128 + f0 + 3] + s4.w * invk;
        }
    }
    if (last) {
        // ---- inline MLP head + log_softmax ----
        __syncthreads();
        if (t < 128) {
            float acc = l1b[t];
            for (int d = 0; d < 256; d++) acc += hr[d] * l1w[t * 256 + d];
            h1[t] = fmaxf(acc, 0.f);
        }
        __syncthreads();
        if (t < 64) {
            float a2 = l2b[t];
            for (int d = 0; d < 128; d++) a2 += h1[d] * l2w[t * 128 + d];
            h2[t] = fmaxf(a2, 0.f);
        }
        __syncthreads();
        if (t < 2) {
            float a3 = l3b[t];
            for (int d = 0; d < 64; d++) a3 += h2[d] * l3w[t * 64 + d];
            lz[t] = a3;
        }
        __syncthreads();
        if (t < 2) {
            float z0 = lz[0], z1 = lz[1];
            float m = fmaxf(z0, z1);
            float lse = m + logf(expf(z0 - m) + expf(z1 - m));
            out[g * 2 + t] = lz[t] - lse;
        }
        return;
    }
    // ---- remap edges (registers) + next-layer deg/cnt histogram ----
    int b0 = g * EPG, gn = g * n, gk = g * k;
    int sr[EPT], dr[EPT];
#pragma unroll
    for (int q = 0; q < EPT; q++) {
        int e = b0 + q * 1024 + t;
        int s = src[e];
        int s2 = -1, d2 = -1;
        if (s >= 0) {
            s2 = nid[s - gn];
            d2 = nid[dst[e] - gn];
            if (s2 >= 0 && d2 >= 0) {
                src[e] = gk + s2;
                dst[e] = gk + d2;
                atomicAdd(&hs[s2], 1);
                atomicAdd(&hc[d2], 1);
            } else {
                src[e] = -1;
                dst[e] = -1;
                s2 = -1;
            }
        }
        sr[q] = s2; dr[q] = d2;
    }
    __syncthreads();
    // ---- two-level exclusive scan of hc; dinv for next layer ----
    int v = (t < k) ? hc[t] : 0;
    if (t < k) dv[t] = rsqrtf((float)hs[t] + 1.0f);
    int s = v;
#pragma unroll
    for (int off = 1; off < 64; off <<= 1) {
        int u = __shfl_up(s, off, 64);
        if (lane >= off) s += u;
    }
    if (lane == 63) wsum[wv] = s;
    __syncthreads();
    if (wv == 0) {
        int ws = (lane < 16) ? wsum[lane] : 0;
#pragma unroll
        for (int off = 1; off < 16; off <<= 1) {
            int u = __shfl_up(ws, off, 64);
            if (lane >= off) ws += u;
        }
        if (lane < 16) wsum[lane] = ws;
    }
    __syncthreads();
    if (t < k) {
        int excl = b0 + s + ((wv > 0) ? wsum[wv - 1] : 0) - v;
        eoff[gk + t] = excl;
        cnt[gk + t] = v;
        dinv[gk + t] = dv[t];
        cur[t] = excl;
    }
    __syncthreads();
#pragma unroll
    for (int q = 0; q < EPT; q++) {
        if (sr[q] >= 0) {
            int pos = atomicAdd(&cur[dr[q]], 1);
            epack[pos] = make_int2(gk + sr[q], __float_as_int(dv[sr[q]] * dv[dr[q]]));
        }
    }
    if (g == 0) {
        if (t < 128) shf[t] = pwN[t] * pwN[t];
        __syncthreads();
        for (int q = 64; q > 0; q >>= 1) {
            if (t < q) shf[t] += shf[t + q];
            __syncthreads();
        }
        if (t == 0) invn[0] = rsqrtf(shf[0]);
    }
}

extern "C" void kernel_launch(void* const* d_in, const int* in_sizes, int n_in,
                              void* d_out, int out_size, void* d_ws, size_t ws_size,
                              hipStream_t stream) {
    const float* x_in = (const float*)d_in[0];
    const int* edge_index = (const int*)d_in[1];
    const float *cw[5], *cb[5], *pw[5];
    for (int i = 0; i < 5; i++) {
        cw[i] = (const float*)d_in[3 + 3 * i];
        cb[i] = (const float*)d_in[4 + 3 * i];
        pw[i] = (const float*)d_in[5 + 3 * i];
    }
    const float* l1w = (const float*)d_in[18];
    const float* l1b = (const float*)d_in[19];
    const float* l2w = (const float*)d_in[20];
    const float* l2b = (const float*)d_in[21];
    const float* l3w = (const float*)d_in[22];
    const float* l3b = (const float*)d_in[23];
    float* out = (float*)d_out;

    char* w = (char*)d_ws;
    float* xA    = (float*)w; w += (size_t)65536 * DIM * 4;
    float* xB    = (float*)w; w += (size_t)65536 * DIM * 4;
    float* xL    = (float*)w; w += (size_t)65536 * DIM * 4;
    int*   src   = (int*)w;   w += (size_t)ETOT * 4;
    int*   dst   = (int*)w;   w += (size_t)ETOT * 4;
    int2*  epack = (int2*)w;  w += (size_t)ETOT * 8;
    int*   cnt   = (int*)w;   w += (size_t)65536 * 4;
    int*   eoff  = (int*)w;   w += (size_t)65536 * 4;
    float* dinv  = (float*)w; w += (size_t)65536 * 4;
    float* score = (float*)w; w += (size_t)65536 * 4;
    float* hsum  = (float*)w; w += (size_t)NB * 256 * 4;
    float* invn  = (float*)w; w += 4;

    init_kernel<<<NB, 1024, 0, stream>>>(edge_index, src, dst, epack, eoff, cnt, dinv,
                                         invn, pw[0], hsum);

    const float* xin = x_in;
    for (int i = 0; i < 5; i++) {
        int n = NS_H[i], k = NS_H[i + 1];
        int N = NB * n;

        linear_kernel<<<N / 64, 256, 0, stream>>>(xin, cw[i], cb[i], xL, N);
        int gpb = (n + 7) / 8;
        fused_agg_kernel<<<NB * gpb, 256, 0, stream>>>(xL, epack, eoff, cnt, dinv, pw[i],
                                                       invn, xA, score, n);
        const float* pwN = (i < 4) ? pw[i + 1] : pw[i];
        pool_kernel<<<NB, 1024, 0, stream>>>(score, xA, xB, hsum, src, dst, epack, eoff,
                                             cnt, dinv, pwN, invn, n, k, (i == 4) ? 1 : 0,
                                             l1w, l1b, l2w, l2b, l3w, l3b, out);

        xin = xB;
    }
}